// Round 1
// baseline (8770.119 us; speedup 1.0000x reference)
//
#include <hip/hip_runtime.h>

// GCN 3-layer forward for MI355X. fp32 everywhere (no fp32 MFMA on CDNA4 -> VALU GEMM).
// Key restructuring: aggregate BEFORE GEMM for layer0 (128-dim < 256-dim),
// aggregate AFTER GEMM for layer2 (2-dim << 256-dim). Bias-before-BN cancels
// exactly, so we add bias in the GEMM epilogue.

#define BN_EPS 1e-5f

// ---------------- edge-index format probe (int32 vs int64 on device) --------
__global__ void detect_i64(const unsigned int* __restrict__ w, int* flag) {
  __shared__ unsigned int red[256];
  unsigned int v = 0;
  int t = threadIdx.x;
  for (int i = t; i < 1024; i += 256) v |= w[2 * i + 1];  // upper words if int64
  red[t] = v;
  __syncthreads();
  for (int s = 128; s > 0; s >>= 1) {
    if (t < s) red[t] |= red[t + s];
    __syncthreads();
  }
  if (t == 0) *flag = (red[0] == 0u) ? 1 : 0;  // all-zero uppers => int64
}

__global__ void convert_idx(const unsigned int* __restrict__ w, const int* __restrict__ flag,
                            int* __restrict__ out, int n) {
  int f = *flag;
  int i = blockIdx.x * blockDim.x + threadIdx.x;
  if (i < n) out[i] = (int)(f ? w[2 * (size_t)i] : w[i]);
}

// ---------------- degree / dinv ----------------------------------------------
__global__ void deg_count(const int* __restrict__ dst, float* __restrict__ deg, int E) {
  int i = blockIdx.x * blockDim.x + threadIdx.x;
  if (i < E) atomicAdd(&deg[dst[i]], 1.0f);
}

__global__ void make_dinv(float* __restrict__ deg, int N) {
  int i = blockIdx.x * blockDim.x + threadIdx.x;
  if (i < N) deg[i] = rsqrtf(deg[i] + 1.0f);  // +1 self-loop; deg>=1 afterwards
}

// ---------------- aggregation: out[n] = dinv[n]^2 * in[n] + sum_e norm*in[src]
__global__ void self_init(const float4* __restrict__ in, float4* __restrict__ out,
                          const float* __restrict__ dinv, int f4shift, int N) {
  long t = (long)blockIdx.x * blockDim.x + threadIdx.x;
  long total = (long)N << f4shift;
  if (t >= total) return;
  int n = (int)(t >> f4shift);
  float w = dinv[n] * dinv[n];
  float4 v = in[t];
  float4 o = {w * v.x, w * v.y, w * v.z, w * v.w};
  out[t] = o;
}

__global__ void agg_edges(const float4* __restrict__ in, float* __restrict__ out,
                          const int* __restrict__ src, const int* __restrict__ dst,
                          const float* __restrict__ dinv, int f4shift, long total) {
  long t = (long)blockIdx.x * blockDim.x + threadIdx.x;
  if (t >= total) return;
  long e = t >> f4shift;
  int c = (int)(t & ((1 << f4shift) - 1));
  int s = src[e], d = dst[e];
  float w = dinv[s] * dinv[d];
  float4 v = in[((long)s << f4shift) + c];
  float* o = out + ((long)d << (f4shift + 2)) + c * 4;
  atomicAdd(o + 0, w * v.x);
  atomicAdd(o + 1, w * v.y);
  atomicAdd(o + 2, w * v.z);
  atomicAdd(o + 3, w * v.w);
}

// ---------------- fp32 tiled GEMM: C[M,NC] = A[M,K] @ W[K,NC] + bias ---------
__global__ __launch_bounds__(256) void gemm_tile(const float* __restrict__ A,
                                                 const float* __restrict__ W,
                                                 const float* __restrict__ bias,
                                                 float* __restrict__ C, int M, int K, int NC) {
  __shared__ float As[32][65];  // padded: 8-way write conflict -> 2-way (free)
  __shared__ float Ws[32][64];
  const int tid = threadIdx.x;
  const int row0 = blockIdx.x * 64;
  const int col0 = blockIdx.y * 64;
  const int tx = tid & 15, ty = tid >> 4;
  float acc[4][4] = {};
  for (int k0 = 0; k0 < K; k0 += 32) {
#pragma unroll
    for (int uu = 0; uu < 2; ++uu) {
      int u = tid + uu * 256;
      // A tile: 64 rows x 32 k, transposed into As[k][m]
      int m = u >> 3, kg = u & 7;
      int row = row0 + m;
      if (row >= M) row = M - 1;  // clamp; store is guarded
      float4 a = *(const float4*)(A + (long)row * K + k0 + kg * 4);
      As[kg * 4 + 0][m] = a.x;
      As[kg * 4 + 1][m] = a.y;
      As[kg * 4 + 2][m] = a.z;
      As[kg * 4 + 3][m] = a.w;
      // W tile: 32 k x 64 cols, direct copy
      int kk = u >> 4, f = u & 15;
      float4 wv = *(const float4*)(W + (long)(k0 + kk) * NC + col0 + f * 4);
      *(float4*)&Ws[kk][f * 4] = wv;
    }
    __syncthreads();
#pragma unroll
    for (int kk = 0; kk < 32; ++kk) {
      float a0 = As[kk][ty * 4 + 0];
      float a1 = As[kk][ty * 4 + 1];
      float a2 = As[kk][ty * 4 + 2];
      float a3 = As[kk][ty * 4 + 3];
      float4 b = *(const float4*)&Ws[kk][tx * 4];
      acc[0][0] += a0 * b.x; acc[0][1] += a0 * b.y; acc[0][2] += a0 * b.z; acc[0][3] += a0 * b.w;
      acc[1][0] += a1 * b.x; acc[1][1] += a1 * b.y; acc[1][2] += a1 * b.z; acc[1][3] += a1 * b.w;
      acc[2][0] += a2 * b.x; acc[2][1] += a2 * b.y; acc[2][2] += a2 * b.z; acc[2][3] += a2 * b.w;
      acc[3][0] += a3 * b.x; acc[3][1] += a3 * b.y; acc[3][2] += a3 * b.z; acc[3][3] += a3 * b.w;
    }
    __syncthreads();
  }
  float4 b4 = *(const float4*)&bias[col0 + tx * 4];
#pragma unroll
  for (int i = 0; i < 4; ++i) {
    int row = row0 + ty * 4 + i;
    if (row < M) {
      float4 o = {acc[i][0] + b4.x, acc[i][1] + b4.y, acc[i][2] + b4.z, acc[i][3] + b4.w};
      *(float4*)(C + (long)row * NC + col0 + tx * 4) = o;
    }
  }
}

// ---------------- BatchNorm (train-mode, biased var) + ReLU ------------------
__global__ void bn_stats(const float* __restrict__ x, float* __restrict__ gsum,
                         float* __restrict__ gsq, int N) {
  int c = threadIdx.x;  // 256 channels == 256 threads
  int r0 = blockIdx.x * 128;
  int r1 = min(r0 + 128, N);
  float s = 0.f, q = 0.f;
  for (int r = r0; r < r1; ++r) {
    float v = x[(long)r * 256 + c];
    s += v;
    q += v * v;
  }
  atomicAdd(&gsum[c], s);
  atomicAdd(&gsq[c], q);
}

__global__ void bn_finalize(const float* __restrict__ gsum, const float* __restrict__ gsq,
                            const float* __restrict__ gamma, const float* __restrict__ beta,
                            float* __restrict__ scale, float* __restrict__ shift, float invN) {
  int c = threadIdx.x;
  float mean = gsum[c] * invN;
  float var = fmaxf(gsq[c] * invN - mean * mean, 0.f);
  float sc = rsqrtf(var + BN_EPS) * gamma[c];
  scale[c] = sc;
  shift[c] = beta[c] - mean * sc;
}

__global__ void bn_apply(const float4* __restrict__ x, float4* __restrict__ h,
                         const float4* __restrict__ scale4, const float4* __restrict__ shift4,
                         long total) {
  long t = (long)blockIdx.x * blockDim.x + threadIdx.x;
  if (t >= total) return;
  float4 v = x[t];
  int c = (int)(t & 63);
  float4 sc = scale4[c], sh = shift4[c];
  float4 o;
  o.x = fmaxf(v.x * sc.x + sh.x, 0.f);
  o.y = fmaxf(v.y * sc.y + sh.y, 0.f);
  o.z = fmaxf(v.z * sc.z + sh.z, 0.f);
  o.w = fmaxf(v.w * sc.w + sh.w, 0.f);
  h[t] = o;
}

// ---------------- layer 2: P = H1 @ W2  (256 -> 2), wave per row -------------
__global__ void gemm_small(const float* __restrict__ H, const float* __restrict__ W2,
                           float* __restrict__ P, int N) {
  int g = blockIdx.x * blockDim.x + threadIdx.x;
  int row = g >> 6;
  int lane = threadIdx.x & 63;
  if (row >= N) return;
  const float* h = H + (long)row * 256;
  float s0 = 0.f, s1 = 0.f;
#pragma unroll
  for (int kk = 0; kk < 4; ++kk) {
    int k = lane + kk * 64;
    float v = h[k];
    s0 += v * W2[2 * k];
    s1 += v * W2[2 * k + 1];
  }
  for (int off = 32; off > 0; off >>= 1) {
    s0 += __shfl_down(s0, off, 64);
    s1 += __shfl_down(s1, off, 64);
  }
  if (lane == 0) {
    P[2 * row] = s0;
    P[2 * row + 1] = s1;
  }
}

__global__ void final_init(const float* __restrict__ P, float* __restrict__ out,
                           const float* __restrict__ dinv, const float* __restrict__ b2, int N) {
  int n = blockIdx.x * blockDim.x + threadIdx.x;
  if (n >= N) return;
  float w = dinv[n] * dinv[n];
  out[2 * n + 0] = w * P[2 * n + 0] + b2[0];
  out[2 * n + 1] = w * P[2 * n + 1] + b2[1];
}

__global__ void final_edges(const float* __restrict__ P, float* __restrict__ out,
                            const int* __restrict__ src, const int* __restrict__ dst,
                            const float* __restrict__ dinv, int E) {
  int e = blockIdx.x * blockDim.x + threadIdx.x;
  if (e >= E) return;
  int s = src[e], d = dst[e];
  float w = dinv[s] * dinv[d];
  atomicAdd(&out[2 * d + 0], w * P[2 * s + 0]);
  atomicAdd(&out[2 * d + 1], w * P[2 * s + 1]);
}

// -----------------------------------------------------------------------------
extern "C" void kernel_launch(void* const* d_in, const int* in_sizes, int n_in,
                              void* d_out, int out_size, void* d_ws, size_t ws_size,
                              hipStream_t stream) {
  const float* x = (const float*)d_in[0];
  const void* eidx = d_in[1];
  const float* W0 = (const float*)d_in[2];
  const float* b0 = (const float*)d_in[3];
  const float* W1 = (const float*)d_in[4];
  const float* b1 = (const float*)d_in[5];
  const float* W2 = (const float*)d_in[6];
  const float* b2 = (const float*)d_in[7];
  const float* gamma0 = (const float*)d_in[8];
  const float* beta0 = (const float*)d_in[9];
  const float* gamma1 = (const float*)d_in[10];
  const float* beta1 = (const float*)d_in[11];

  const int N = in_sizes[0] / 128;  // 100000
  const int E = in_sizes[1] / 2;    // 1600000
  float* out = (float*)d_out;

  // workspace layout (bytes), all 16B-aligned
  char* base = (char*)d_ws;
  const size_t o_idx = 0;                          // 2E int32  = 12.8 MB
  const size_t o_dinv = o_idx + (size_t)2 * E * 4; // N f32     = 0.4 MB
  const size_t o_flag = o_dinv + (size_t)N * 4;
  const size_t o_stats = (o_flag + 4 + 255) & ~(size_t)255;  // 4x256 f32
  const size_t o_P = (o_stats + 4096 + 255) & ~(size_t)255;  // N*2 f32
  const size_t o_A = (o_P + (size_t)N * 2 * 4 + 255) & ~(size_t)255;   // N*256 f32
  const size_t o_B = o_A + (size_t)N * 256 * 4;                        // N*256 f32

  int* idx32 = (int*)(base + o_idx);
  int* srcI = idx32;
  int* dstI = idx32 + E;
  float* dinv = (float*)(base + o_dinv);
  int* flag = (int*)(base + o_flag);
  float* gsum = (float*)(base + o_stats);
  float* gsq = gsum + 256;
  float* scale = gsum + 512;
  float* shift = gsum + 768;
  float* P = (float*)(base + o_P);
  float* bufA = (float*)(base + o_A);
  float* bufB = (float*)(base + o_B);

  auto cdiv = [](long a, long b) { return (int)((a + b - 1) / b); };
  const float invN = 1.0f / (float)N;

  // 1. edge index: detect dtype, convert to int32 src/dst
  hipLaunchKernelGGL(detect_i64, dim3(1), dim3(256), 0, stream, (const unsigned int*)eidx, flag);
  hipLaunchKernelGGL(convert_idx, dim3(cdiv(2L * E, 256)), dim3(256), 0, stream,
                     (const unsigned int*)eidx, flag, idx32, 2 * E);

  // 2. degrees -> dinv (in place)
  hipMemsetAsync(dinv, 0, (size_t)N * 4, stream);
  hipLaunchKernelGGL(deg_count, dim3(cdiv(E, 256)), dim3(256), 0, stream, dstI, dinv, E);
  hipLaunchKernelGGL(make_dinv, dim3(cdiv(N, 256)), dim3(256), 0, stream, dinv, N);

  // 3. layer 0: AX = A_hat @ x  (128-dim), then GEMM -> out0 (bufB)
  hipLaunchKernelGGL(self_init, dim3(cdiv((long)N * 32, 256)), dim3(256), 0, stream,
                     (const float4*)x, (float4*)bufA, dinv, 5, N);
  hipLaunchKernelGGL(agg_edges, dim3(cdiv((long)E * 32, 256)), dim3(256), 0, stream,
                     (const float4*)x, bufA, srcI, dstI, dinv, 5, (long)E * 32);
  hipLaunchKernelGGL(gemm_tile, dim3(cdiv(N, 64), 4), dim3(256), 0, stream, bufA, W0, b0, bufB,
                     N, 128, 256);

  // 4. BN0 + ReLU: bufB -> bufA (= H0)
  hipMemsetAsync(gsum, 0, 2048, stream);
  hipLaunchKernelGGL(bn_stats, dim3(cdiv(N, 128)), dim3(256), 0, stream, bufB, gsum, gsq, N);
  hipLaunchKernelGGL(bn_finalize, dim3(1), dim3(256), 0, stream, gsum, gsq, gamma0, beta0, scale,
                     shift, invN);
  hipLaunchKernelGGL(bn_apply, dim3(cdiv((long)N * 64, 256)), dim3(256), 0, stream,
                     (const float4*)bufB, (float4*)bufA, (const float4*)scale, (const float4*)shift,
                     (long)N * 64);

  // 5. layer 1: AH0 = A_hat @ H0 (256-dim) -> bufB; GEMM -> out1 (bufA)
  hipLaunchKernelGGL(self_init, dim3(cdiv((long)N * 64, 256)), dim3(256), 0, stream,
                     (const float4*)bufA, (float4*)bufB, dinv, 6, N);
  hipLaunchKernelGGL(agg_edges, dim3(cdiv((long)E * 64, 256)), dim3(256), 0, stream,
                     (const float4*)bufA, bufB, srcI, dstI, dinv, 6, (long)E * 64);
  hipLaunchKernelGGL(gemm_tile, dim3(cdiv(N, 64), 4), dim3(256), 0, stream, bufB, W1, b1, bufA,
                     N, 256, 256);

  // 6. BN1 + ReLU: bufA -> bufB (= H1)
  hipMemsetAsync(gsum, 0, 2048, stream);
  hipLaunchKernelGGL(bn_stats, dim3(cdiv(N, 128)), dim3(256), 0, stream, bufA, gsum, gsq, N);
  hipLaunchKernelGGL(bn_finalize, dim3(1), dim3(256), 0, stream, gsum, gsq, gamma1, beta1, scale,
                     shift, invN);
  hipLaunchKernelGGL(bn_apply, dim3(cdiv((long)N * 64, 256)), dim3(256), 0, stream,
                     (const float4*)bufA, (float4*)bufB, (const float4*)scale, (const float4*)shift,
                     (long)N * 64);

  // 7. layer 2: P = H1 @ W2 (256->2), then 2-dim aggregation into d_out
  hipLaunchKernelGGL(gemm_small, dim3(cdiv((long)N * 64, 256)), dim3(256), 0, stream, bufB, W2, P,
                     N);
  hipLaunchKernelGGL(final_init, dim3(cdiv(N, 256)), dim3(256), 0, stream, P, out, dinv, b2, N);
  hipLaunchKernelGGL(final_edges, dim3(cdiv(E, 256)), dim3(256), 0, stream, P, out, srcI, dstI,
                     dinv, E);
}

// Round 2
// 1062.586 us; speedup vs baseline: 8.2536x; 8.2536x over previous
//
#include <hip/hip_runtime.h>

// GCN 3-layer forward, MI355X. Round 2: CSR-gather aggregation (replaces
// atomic scatter, which was 7.9ms of 8.77ms: atomic-throughput-bound at
// 77 G-atomics/s, 6.4GB of RMW write traffic).
// Structure: agg BEFORE GEMM for layer0 (128-dim), agg AFTER GEMM for
// layer2 (2-dim). Bias folded into GEMM epilogue (cancels in BN anyway).

#define BN_EPS 1e-5f

// ---------------- edge-index format probe (int32 vs int64 on device) --------
__global__ void detect_i64(const unsigned int* __restrict__ w, int* flag) {
  __shared__ unsigned int red[256];
  unsigned int v = 0;
  int t = threadIdx.x;
  for (int i = t; i < 1024; i += 256) v |= w[2 * i + 1];  // upper words if int64
  red[t] = v;
  __syncthreads();
  for (int s = 128; s > 0; s >>= 1) {
    if (t < s) red[t] |= red[t + s];
    __syncthreads();
  }
  if (t == 0) *flag = (red[0] == 0u) ? 1 : 0;  // all-zero uppers => int64
}

__global__ void convert_idx(const unsigned int* __restrict__ w, const int* __restrict__ flag,
                            int* __restrict__ out, int n) {
  int f = *flag;
  int i = blockIdx.x * blockDim.x + threadIdx.x;
  if (i < n) out[i] = (int)(f ? w[2 * (size_t)i] : w[i]);
}

// ---------------- degree / dinv ----------------------------------------------
__global__ void deg_count(const int* __restrict__ dst, int* __restrict__ deg, int E) {
  int i = blockIdx.x * blockDim.x + threadIdx.x;
  if (i < E) atomicAdd(&deg[dst[i]], 1);
}

__global__ void make_dinv(const int* __restrict__ deg, float* __restrict__ dinv, int N) {
  int i = blockIdx.x * blockDim.x + threadIdx.x;
  if (i < N) dinv[i] = rsqrtf((float)deg[i] + 1.0f);  // +1 self-loop
}

// ---------------- prefix scan (tile = 1024, needs N <= 262144) ---------------
__global__ void scan_partial(const int* __restrict__ deg, int* __restrict__ blksum, int N) {
  __shared__ int s[256];
  int b = blockIdx.x, t = threadIdx.x;
  int base = b * 1024 + t * 4;
  int v = 0;
#pragma unroll
  for (int k = 0; k < 4; ++k) {
    int i = base + k;
    if (i < N) v += deg[i];
  }
  s[t] = v;
  __syncthreads();
  for (int st = 128; st > 0; st >>= 1) {
    if (t < st) s[t] += s[t + st];
    __syncthreads();
  }
  if (t == 0) blksum[b] = s[0];
}

__global__ void scan_blk(int* __restrict__ blksum, int B) {  // in-place exclusive
  __shared__ int s[256];
  int t = threadIdx.x;
  int v = (t < B) ? blksum[t] : 0;
  s[t] = v;
  __syncthreads();
  for (int off = 1; off < 256; off <<= 1) {
    int u = (t >= off) ? s[t - off] : 0;
    __syncthreads();
    s[t] += u;
    __syncthreads();
  }
  if (t < B) blksum[t] = s[t] - v;  // exclusive
}

__global__ void scan_final(const int* __restrict__ deg, const int* __restrict__ blkoff,
                           int* __restrict__ rowptr, int N, int E) {
  __shared__ int s[256];
  int b = blockIdx.x, t = threadIdx.x;
  int base = b * 1024 + t * 4;
  int v[4];
  int sum = 0;
#pragma unroll
  for (int k = 0; k < 4; ++k) {
    int i = base + k;
    v[k] = (i < N) ? deg[i] : 0;
    sum += v[k];
  }
  s[t] = sum;
  __syncthreads();
  for (int off = 1; off < 256; off <<= 1) {
    int u = (t >= off) ? s[t - off] : 0;
    __syncthreads();
    s[t] += u;
    __syncthreads();
  }
  int ex = s[t] - sum + blkoff[b];
#pragma unroll
  for (int k = 0; k < 4; ++k) {
    int i = base + k;
    if (i < N) {
      rowptr[i] = ex;
      ex += v[k];
    }
  }
  if (b == 0 && t == 0) rowptr[N] = E;
}

// ---------------- CSR scatter -------------------------------------------------
__global__ void csr_scatter(const int* __restrict__ src, const int* __restrict__ dst,
                            const float* __restrict__ dinv, const int* __restrict__ rowptr,
                            int* __restrict__ fill, int* __restrict__ col,
                            float* __restrict__ wgt, int E) {
  int e = blockIdx.x * blockDim.x + threadIdx.x;
  if (e >= E) return;
  int s = src[e], d = dst[e];
  int pos = atomicAdd(&fill[d], 1);
  int slot = rowptr[d] + pos;
  col[slot] = s;
  wgt[slot] = dinv[s] * dinv[d];
}

// ---------------- gather aggregation: out[n] = dinv[n]^2 in[n] + sum w*in[src]
// LPN lanes per node, each lane owns one float4 (F = 4*LPN).
template <int LPN>
__global__ void agg_gather(const float4* __restrict__ in, float4* __restrict__ out,
                           const int* __restrict__ rowptr, const int* __restrict__ col,
                           const float* __restrict__ wgt, const float* __restrict__ dinv, int N) {
  long g = (long)blockIdx.x * blockDim.x + threadIdx.x;
  int n = (int)(g / LPN);
  int lane = (int)(g & (LPN - 1));
  if (n >= N) return;
  float ws = dinv[n];
  ws *= ws;
  float4 v = in[(long)n * LPN + lane];
  float4 acc = {ws * v.x, ws * v.y, ws * v.z, ws * v.w};
  int beg = rowptr[n], end = rowptr[n + 1];
  int j = beg;
  for (; j + 1 < end; j += 2) {
    int s0 = col[j], s1 = col[j + 1];
    float w0 = wgt[j], w1 = wgt[j + 1];
    float4 a = in[(long)s0 * LPN + lane];
    float4 b = in[(long)s1 * LPN + lane];
    acc.x += w0 * a.x + w1 * b.x;
    acc.y += w0 * a.y + w1 * b.y;
    acc.z += w0 * a.z + w1 * b.z;
    acc.w += w0 * a.w + w1 * b.w;
  }
  if (j < end) {
    int s0 = col[j];
    float w0 = wgt[j];
    float4 a = in[(long)s0 * LPN + lane];
    acc.x += w0 * a.x;
    acc.y += w0 * a.y;
    acc.z += w0 * a.z;
    acc.w += w0 * a.w;
  }
  out[(long)n * LPN + lane] = acc;
}

// ---------------- fp32 tiled GEMM: C[M,NC] = A[M,K] @ W[K,NC] + bias ---------
__global__ __launch_bounds__(256) void gemm_tile(const float* __restrict__ A,
                                                 const float* __restrict__ W,
                                                 const float* __restrict__ bias,
                                                 float* __restrict__ C, int M, int K, int NC) {
  __shared__ float As[32][65];
  __shared__ float Ws[32][64];
  const int tid = threadIdx.x;
  const int row0 = blockIdx.x * 64;
  const int col0 = blockIdx.y * 64;
  const int tx = tid & 15, ty = tid >> 4;
  float acc[4][4] = {};
  for (int k0 = 0; k0 < K; k0 += 32) {
#pragma unroll
    for (int uu = 0; uu < 2; ++uu) {
      int u = tid + uu * 256;
      int m = u >> 3, kg = u & 7;
      int row = row0 + m;
      if (row >= M) row = M - 1;
      float4 a = *(const float4*)(A + (long)row * K + k0 + kg * 4);
      As[kg * 4 + 0][m] = a.x;
      As[kg * 4 + 1][m] = a.y;
      As[kg * 4 + 2][m] = a.z;
      As[kg * 4 + 3][m] = a.w;
      int kk = u >> 4, f = u & 15;
      float4 wv = *(const float4*)(W + (long)(k0 + kk) * NC + col0 + f * 4);
      *(float4*)&Ws[kk][f * 4] = wv;
    }
    __syncthreads();
#pragma unroll
    for (int kk = 0; kk < 32; ++kk) {
      float a0 = As[kk][ty * 4 + 0];
      float a1 = As[kk][ty * 4 + 1];
      float a2 = As[kk][ty * 4 + 2];
      float a3 = As[kk][ty * 4 + 3];
      float4 b = *(const float4*)&Ws[kk][tx * 4];
      acc[0][0] += a0 * b.x; acc[0][1] += a0 * b.y; acc[0][2] += a0 * b.z; acc[0][3] += a0 * b.w;
      acc[1][0] += a1 * b.x; acc[1][1] += a1 * b.y; acc[1][2] += a1 * b.z; acc[1][3] += a1 * b.w;
      acc[2][0] += a2 * b.x; acc[2][1] += a2 * b.y; acc[2][2] += a2 * b.z; acc[2][3] += a2 * b.w;
      acc[3][0] += a3 * b.x; acc[3][1] += a3 * b.y; acc[3][2] += a3 * b.z; acc[3][3] += a3 * b.w;
    }
    __syncthreads();
  }
  float4 b4 = *(const float4*)&bias[col0 + tx * 4];
#pragma unroll
  for (int i = 0; i < 4; ++i) {
    int row = row0 + ty * 4 + i;
    if (row < M) {
      float4 o = {acc[i][0] + b4.x, acc[i][1] + b4.y, acc[i][2] + b4.z, acc[i][3] + b4.w};
      *(float4*)(C + (long)row * NC + col0 + tx * 4) = o;
    }
  }
}

// ---------------- BatchNorm (train-mode, biased var) + ReLU ------------------
__global__ void bn_stats(const float* __restrict__ x, float* __restrict__ gsum,
                         float* __restrict__ gsq, int N) {
  int c = threadIdx.x;
  int r0 = blockIdx.x * 128;
  int r1 = min(r0 + 128, N);
  float s = 0.f, q = 0.f;
  for (int r = r0; r < r1; ++r) {
    float v = x[(long)r * 256 + c];
    s += v;
    q += v * v;
  }
  atomicAdd(&gsum[c], s);
  atomicAdd(&gsq[c], q);
}

__global__ void bn_finalize(const float* __restrict__ gsum, const float* __restrict__ gsq,
                            const float* __restrict__ gamma, const float* __restrict__ beta,
                            float* __restrict__ scale, float* __restrict__ shift, float invN) {
  int c = threadIdx.x;
  float mean = gsum[c] * invN;
  float var = fmaxf(gsq[c] * invN - mean * mean, 0.f);
  float sc = rsqrtf(var + BN_EPS) * gamma[c];
  scale[c] = sc;
  shift[c] = beta[c] - mean * sc;
}

__global__ void bn_apply(const float4* __restrict__ x, float4* __restrict__ h,
                         const float4* __restrict__ scale4, const float4* __restrict__ shift4,
                         long total) {
  long t = (long)blockIdx.x * blockDim.x + threadIdx.x;
  if (t >= total) return;
  float4 v = x[t];
  int c = (int)(t & 63);
  float4 sc = scale4[c], sh = shift4[c];
  float4 o;
  o.x = fmaxf(v.x * sc.x + sh.x, 0.f);
  o.y = fmaxf(v.y * sc.y + sh.y, 0.f);
  o.z = fmaxf(v.z * sc.z + sh.z, 0.f);
  o.w = fmaxf(v.w * sc.w + sh.w, 0.f);
  h[t] = o;
}

// ---------------- layer 2: P = H1 @ W2 (256 -> 2), wave per row --------------
__global__ void gemm_small(const float* __restrict__ H, const float* __restrict__ W2,
                           float* __restrict__ P, int N) {
  int g = blockIdx.x * blockDim.x + threadIdx.x;
  int row = g >> 6;
  int lane = threadIdx.x & 63;
  if (row >= N) return;
  const float* h = H + (long)row * 256;
  float s0 = 0.f, s1 = 0.f;
#pragma unroll
  for (int kk = 0; kk < 4; ++kk) {
    int k = lane + kk * 64;
    float v = h[k];
    s0 += v * W2[2 * k];
    s1 += v * W2[2 * k + 1];
  }
  for (int off = 32; off > 0; off >>= 1) {
    s0 += __shfl_down(s0, off, 64);
    s1 += __shfl_down(s1, off, 64);
  }
  if (lane == 0) {
    P[2 * row] = s0;
    P[2 * row + 1] = s1;
  }
}

__global__ void final_gather(const float* __restrict__ P, float* __restrict__ out,
                             const int* __restrict__ rowptr, const int* __restrict__ col,
                             const float* __restrict__ wgt, const float* __restrict__ dinv,
                             const float* __restrict__ b2, int N) {
  int n = blockIdx.x * blockDim.x + threadIdx.x;
  if (n >= N) return;
  float w = dinv[n] * dinv[n];
  float a0 = w * P[2 * n + 0];
  float a1 = w * P[2 * n + 1];
  int end = rowptr[n + 1];
  for (int j = rowptr[n]; j < end; ++j) {
    int s = col[j];
    float ww = wgt[j];
    a0 += ww * P[2 * s + 0];
    a1 += ww * P[2 * s + 1];
  }
  out[2 * n + 0] = a0 + b2[0];
  out[2 * n + 1] = a1 + b2[1];
}

// -----------------------------------------------------------------------------
extern "C" void kernel_launch(void* const* d_in, const int* in_sizes, int n_in,
                              void* d_out, int out_size, void* d_ws, size_t ws_size,
                              hipStream_t stream) {
  const float* x = (const float*)d_in[0];
  const void* eidx = d_in[1];
  const float* W0 = (const float*)d_in[2];
  const float* b0 = (const float*)d_in[3];
  const float* W1 = (const float*)d_in[4];
  const float* b1 = (const float*)d_in[5];
  const float* W2 = (const float*)d_in[6];
  const float* b2 = (const float*)d_in[7];
  const float* gamma0 = (const float*)d_in[8];
  const float* beta0 = (const float*)d_in[9];
  const float* gamma1 = (const float*)d_in[10];
  const float* beta1 = (const float*)d_in[11];

  const int N = in_sizes[0] / 128;  // 100000
  const int E = in_sizes[1] / 2;    // 1600000
  float* out = (float*)d_out;

  // workspace layout (bytes); idx32 overlaps bufB (dead before bufB is written)
  char* base = (char*)d_ws;
  size_t off = 0;
  auto alloc = [&](size_t bytes) {
    size_t o = off;
    off = (off + bytes + 255) & ~(size_t)255;
    return o;
  };
  const size_t o_col = alloc((size_t)E * 4);
  const size_t o_wgt = alloc((size_t)E * 4);
  const size_t o_rowptr = alloc((size_t)(N + 1) * 4);
  const size_t o_deg = alloc((size_t)N * 4);
  const size_t o_fill = alloc((size_t)N * 4);
  const size_t o_dinv = alloc((size_t)N * 4);
  const size_t o_blk = alloc(1024 * 4);
  const size_t o_flag = alloc(256);
  const size_t o_stats = alloc(4096);
  const size_t o_P = alloc((size_t)N * 2 * 4);
  const size_t o_A = alloc((size_t)N * 256 * 4);
  const size_t o_B = alloc((size_t)N * 256 * 4);

  int* col = (int*)(base + o_col);
  float* wgt = (float*)(base + o_wgt);
  int* rowptr = (int*)(base + o_rowptr);
  int* deg = (int*)(base + o_deg);
  int* fill = (int*)(base + o_fill);
  float* dinv = (float*)(base + o_dinv);
  int* blk = (int*)(base + o_blk);
  int* flag = (int*)(base + o_flag);
  float* gsum = (float*)(base + o_stats);
  float* gsq = gsum + 256;
  float* scale = gsum + 512;
  float* shift = gsum + 768;
  float* P = (float*)(base + o_P);
  float* bufA = (float*)(base + o_A);
  float* bufB = (float*)(base + o_B);
  int* idx32 = (int*)(base + o_B);  // overlap: dead before bufB first written
  int* srcI = idx32;
  int* dstI = idx32 + E;

  auto cdiv = [](long a, long b) { return (int)((a + b - 1) / b); };
  const float invN = 1.0f / (float)N;
  const int B1 = cdiv(N, 1024);

  // 1. edge index -> int32 src/dst (in bufB region)
  hipLaunchKernelGGL(detect_i64, dim3(1), dim3(256), 0, stream, (const unsigned int*)eidx, flag);
  hipLaunchKernelGGL(convert_idx, dim3(cdiv(2L * E, 256)), dim3(256), 0, stream,
                     (const unsigned int*)eidx, flag, idx32, 2 * E);

  // 2. degrees -> dinv; CSR build
  hipMemsetAsync(deg, 0, (size_t)N * 4, stream);
  hipMemsetAsync(fill, 0, (size_t)N * 4, stream);
  hipLaunchKernelGGL(deg_count, dim3(cdiv(E, 256)), dim3(256), 0, stream, dstI, deg, E);
  hipLaunchKernelGGL(make_dinv, dim3(cdiv(N, 256)), dim3(256), 0, stream, deg, dinv, N);
  hipLaunchKernelGGL(scan_partial, dim3(B1), dim3(256), 0, stream, deg, blk, N);
  hipLaunchKernelGGL(scan_blk, dim3(1), dim3(256), 0, stream, blk, B1);
  hipLaunchKernelGGL(scan_final, dim3(B1), dim3(256), 0, stream, deg, blk, rowptr, N, E);
  hipLaunchKernelGGL(csr_scatter, dim3(cdiv(E, 256)), dim3(256), 0, stream, srcI, dstI, dinv,
                     rowptr, fill, col, wgt, E);

  // 3. layer 0: AX = A_hat @ x (128-dim gather), then GEMM -> bufB
  hipLaunchKernelGGL((agg_gather<32>), dim3(cdiv((long)N * 32, 256)), dim3(256), 0, stream,
                     (const float4*)x, (float4*)bufA, rowptr, col, wgt, dinv, N);
  hipLaunchKernelGGL(gemm_tile, dim3(cdiv(N, 64), 4), dim3(256), 0, stream, bufA, W0, b0, bufB,
                     N, 128, 256);

  // 4. BN0 + ReLU: bufB -> bufA (= H0)
  hipMemsetAsync(gsum, 0, 2048, stream);
  hipLaunchKernelGGL(bn_stats, dim3(cdiv(N, 128)), dim3(256), 0, stream, bufB, gsum, gsq, N);
  hipLaunchKernelGGL(bn_finalize, dim3(1), dim3(256), 0, stream, gsum, gsq, gamma0, beta0, scale,
                     shift, invN);
  hipLaunchKernelGGL(bn_apply, dim3(cdiv((long)N * 64, 256)), dim3(256), 0, stream,
                     (const float4*)bufB, (float4*)bufA, (const float4*)scale, (const float4*)shift,
                     (long)N * 64);

  // 5. layer 1: AH0 (256-dim gather) -> bufB; GEMM -> bufA
  hipLaunchKernelGGL((agg_gather<64>), dim3(cdiv((long)N * 64, 256)), dim3(256), 0, stream,
                     (const float4*)bufA, (float4*)bufB, rowptr, col, wgt, dinv, N);
  hipLaunchKernelGGL(gemm_tile, dim3(cdiv(N, 64), 4), dim3(256), 0, stream, bufB, W1, b1, bufA,
                     N, 256, 256);

  // 6. BN1 + ReLU: bufA -> bufB (= H1)
  hipMemsetAsync(gsum, 0, 2048, stream);
  hipLaunchKernelGGL(bn_stats, dim3(cdiv(N, 128)), dim3(256), 0, stream, bufA, gsum, gsq, N);
  hipLaunchKernelGGL(bn_finalize, dim3(1), dim3(256), 0, stream, gsum, gsq, gamma1, beta1, scale,
                     shift, invN);
  hipLaunchKernelGGL(bn_apply, dim3(cdiv((long)N * 64, 256)), dim3(256), 0, stream,
                     (const float4*)bufA, (float4*)bufB, (const float4*)scale, (const float4*)shift,
                     (long)N * 64);

  // 7. layer 2: P = H1 @ W2 (256->2), then 2-dim CSR gather into d_out
  hipLaunchKernelGGL(gemm_small, dim3(cdiv((long)N * 64, 256)), dim3(256), 0, stream, bufB, W2, P,
                     N);
  hipLaunchKernelGGL(final_gather, dim3(cdiv(N, 256)), dim3(256), 0, stream, P, out, rowptr, col,
                     wgt, dinv, b2, N);
}

// Round 3
// 869.443 us; speedup vs baseline: 10.0871x; 1.2221x over previous
//
#include <hip/hip_runtime.h>
#include <hip/hip_fp16.h>

// GCN 3-layer forward, MI355X. Round 3: fp16 feature tables for gathers.
// R1: atomic scatter was 7.9ms (atomic-RMW bound). R2: CSR gather -> 1063us;
// top dispatch agg_gather<64> 248us, traffic-bound on gathered rows.
// R3: gathers + thin-GEMM inputs read fp16 (half the bytes); fp32 accumulate.

#define BN_EPS 1e-5f

union HF4 { float4 f; __half2 h[4]; };  // 8 halves in 16B

// ---------------- edge-index format probe (int32 vs int64 on device) --------
__global__ void detect_i64(const unsigned int* __restrict__ w, int* flag) {
  __shared__ unsigned int red[256];
  unsigned int v = 0;
  int t = threadIdx.x;
  for (int i = t; i < 1024; i += 256) v |= w[2 * i + 1];
  red[t] = v;
  __syncthreads();
  for (int s = 128; s > 0; s >>= 1) {
    if (t < s) red[t] |= red[t + s];
    __syncthreads();
  }
  if (t == 0) *flag = (red[0] == 0u) ? 1 : 0;
}

__global__ void convert_idx(const unsigned int* __restrict__ w, const int* __restrict__ flag,
                            int* __restrict__ out, int n) {
  int f = *flag;
  int i = blockIdx.x * blockDim.x + threadIdx.x;
  if (i < n) out[i] = (int)(f ? w[2 * (size_t)i] : w[i]);
}

// ---------------- degree / dinv ----------------------------------------------
__global__ void deg_count(const int* __restrict__ dst, int* __restrict__ deg, int E) {
  int i = blockIdx.x * blockDim.x + threadIdx.x;
  if (i < E) atomicAdd(&deg[dst[i]], 1);
}

__global__ void make_dinv(const int* __restrict__ deg, float* __restrict__ dinv, int N) {
  int i = blockIdx.x * blockDim.x + threadIdx.x;
  if (i < N) dinv[i] = rsqrtf((float)deg[i] + 1.0f);
}

// ---------------- prefix scan (tile = 1024) ----------------------------------
__global__ void scan_partial(const int* __restrict__ deg, int* __restrict__ blksum, int N) {
  __shared__ int s[256];
  int b = blockIdx.x, t = threadIdx.x;
  int base = b * 1024 + t * 4;
  int v = 0;
#pragma unroll
  for (int k = 0; k < 4; ++k) {
    int i = base + k;
    if (i < N) v += deg[i];
  }
  s[t] = v;
  __syncthreads();
  for (int st = 128; st > 0; st >>= 1) {
    if (t < st) s[t] += s[t + st];
    __syncthreads();
  }
  if (t == 0) blksum[b] = s[0];
}

__global__ void scan_blk(int* __restrict__ blksum, int B) {
  __shared__ int s[256];
  int t = threadIdx.x;
  int v = (t < B) ? blksum[t] : 0;
  s[t] = v;
  __syncthreads();
  for (int off = 1; off < 256; off <<= 1) {
    int u = (t >= off) ? s[t - off] : 0;
    __syncthreads();
    s[t] += u;
    __syncthreads();
  }
  if (t < B) blksum[t] = s[t] - v;
}

__global__ void scan_final(const int* __restrict__ deg, const int* __restrict__ blkoff,
                           int* __restrict__ rowptr, int N, int E) {
  __shared__ int s[256];
  int b = blockIdx.x, t = threadIdx.x;
  int base = b * 1024 + t * 4;
  int v[4];
  int sum = 0;
#pragma unroll
  for (int k = 0; k < 4; ++k) {
    int i = base + k;
    v[k] = (i < N) ? deg[i] : 0;
    sum += v[k];
  }
  s[t] = sum;
  __syncthreads();
  for (int off = 1; off < 256; off <<= 1) {
    int u = (t >= off) ? s[t - off] : 0;
    __syncthreads();
    s[t] += u;
    __syncthreads();
  }
  int ex = s[t] - sum + blkoff[b];
#pragma unroll
  for (int k = 0; k < 4; ++k) {
    int i = base + k;
    if (i < N) {
      rowptr[i] = ex;
      ex += v[k];
    }
  }
  if (b == 0 && t == 0) rowptr[N] = E;
}

// ---------------- CSR scatter -------------------------------------------------
__global__ void csr_scatter(const int* __restrict__ src, const int* __restrict__ dst,
                            const float* __restrict__ dinv, const int* __restrict__ rowptr,
                            int* __restrict__ fill, int* __restrict__ col,
                            float* __restrict__ wgt, int E) {
  int e = blockIdx.x * blockDim.x + threadIdx.x;
  if (e >= E) return;
  int s = src[e], d = dst[e];
  int pos = atomicAdd(&fill[d], 1);
  int slot = rowptr[d] + pos;
  col[slot] = s;
  wgt[slot] = dinv[s] * dinv[d];
}

// ---------------- fp32 -> fp16 convert (8 elems/thread) ----------------------
__global__ void f32_to_f16(const float4* __restrict__ in, float4* __restrict__ outh, long n8) {
  long t = (long)blockIdx.x * blockDim.x + threadIdx.x;
  if (t >= n8) return;
  float4 a = in[2 * t], b = in[2 * t + 1];
  HF4 o;
  o.h[0] = __floats2half2_rn(a.x, a.y);
  o.h[1] = __floats2half2_rn(a.z, a.w);
  o.h[2] = __floats2half2_rn(b.x, b.y);
  o.h[3] = __floats2half2_rn(b.z, b.w);
  outh[t] = o.f;
}

// ---------------- gather aggregation (fp16 in, fp32 out) ---------------------
// LPN lanes per node, each lane owns 8 halves (16B). F = 8*LPN.
template <int LPN>
__global__ void agg_gather_h(const float4* __restrict__ inh, float4* __restrict__ out,
                             const int* __restrict__ rowptr, const int* __restrict__ col,
                             const float* __restrict__ wgt, const float* __restrict__ dinv,
                             int N) {
  long g = (long)blockIdx.x * blockDim.x + threadIdx.x;
  int n = (int)(g / LPN);
  int lane = (int)(g & (LPN - 1));
  if (n >= N) return;
  float ws = dinv[n];
  ws *= ws;
  float acc[8];
  {
    HF4 u;
    u.f = inh[(long)n * LPN + lane];
#pragma unroll
    for (int i = 0; i < 4; ++i) {
      float2 f = __half22float2(u.h[i]);
      acc[2 * i] = ws * f.x;
      acc[2 * i + 1] = ws * f.y;
    }
  }
  int beg = rowptr[n], end = rowptr[n + 1];
  int j = beg;
  for (; j + 1 < end; j += 2) {
    int s0 = col[j], s1 = col[j + 1];
    float w0 = wgt[j], w1 = wgt[j + 1];
    HF4 a, b;
    a.f = inh[(long)s0 * LPN + lane];
    b.f = inh[(long)s1 * LPN + lane];
#pragma unroll
    for (int i = 0; i < 4; ++i) {
      float2 fa = __half22float2(a.h[i]);
      float2 fb = __half22float2(b.h[i]);
      acc[2 * i] += w0 * fa.x + w1 * fb.x;
      acc[2 * i + 1] += w0 * fa.y + w1 * fb.y;
    }
  }
  if (j < end) {
    int s0 = col[j];
    float w0 = wgt[j];
    HF4 a;
    a.f = inh[(long)s0 * LPN + lane];
#pragma unroll
    for (int i = 0; i < 4; ++i) {
      float2 fa = __half22float2(a.h[i]);
      acc[2 * i] += w0 * fa.x;
      acc[2 * i + 1] += w0 * fa.y;
    }
  }
  float4 o0 = {acc[0], acc[1], acc[2], acc[3]};
  float4 o1 = {acc[4], acc[5], acc[6], acc[7]};
  out[((long)n * LPN + lane) * 2] = o0;
  out[((long)n * LPN + lane) * 2 + 1] = o1;
}

// ---------------- fp32 tiled GEMM: C[M,NC] = A[M,K] @ W[K,NC] + bias ---------
__global__ __launch_bounds__(256) void gemm_tile(const float* __restrict__ A,
                                                 const float* __restrict__ W,
                                                 const float* __restrict__ bias,
                                                 float* __restrict__ C, int M, int K, int NC) {
  __shared__ float As[32][65];
  __shared__ float Ws[32][64];
  const int tid = threadIdx.x;
  const int row0 = blockIdx.x * 64;
  const int col0 = blockIdx.y * 64;
  const int tx = tid & 15, ty = tid >> 4;
  float acc[4][4] = {};
  for (int k0 = 0; k0 < K; k0 += 32) {
#pragma unroll
    for (int uu = 0; uu < 2; ++uu) {
      int u = tid + uu * 256;
      int m = u >> 3, kg = u & 7;
      int row = row0 + m;
      if (row >= M) row = M - 1;
      float4 a = *(const float4*)(A + (long)row * K + k0 + kg * 4);
      As[kg * 4 + 0][m] = a.x;
      As[kg * 4 + 1][m] = a.y;
      As[kg * 4 + 2][m] = a.z;
      As[kg * 4 + 3][m] = a.w;
      int kk = u >> 4, f = u & 15;
      float4 wv = *(const float4*)(W + (long)(k0 + kk) * NC + col0 + f * 4);
      *(float4*)&Ws[kk][f * 4] = wv;
    }
    __syncthreads();
#pragma unroll
    for (int kk = 0; kk < 32; ++kk) {
      float a0 = As[kk][ty * 4 + 0];
      float a1 = As[kk][ty * 4 + 1];
      float a2 = As[kk][ty * 4 + 2];
      float a3 = As[kk][ty * 4 + 3];
      float4 b = *(const float4*)&Ws[kk][tx * 4];
      acc[0][0] += a0 * b.x; acc[0][1] += a0 * b.y; acc[0][2] += a0 * b.z; acc[0][3] += a0 * b.w;
      acc[1][0] += a1 * b.x; acc[1][1] += a1 * b.y; acc[1][2] += a1 * b.z; acc[1][3] += a1 * b.w;
      acc[2][0] += a2 * b.x; acc[2][1] += a2 * b.y; acc[2][2] += a2 * b.z; acc[2][3] += a2 * b.w;
      acc[3][0] += a3 * b.x; acc[3][1] += a3 * b.y; acc[3][2] += a3 * b.z; acc[3][3] += a3 * b.w;
    }
    __syncthreads();
  }
  float4 b4 = *(const float4*)&bias[col0 + tx * 4];
#pragma unroll
  for (int i = 0; i < 4; ++i) {
    int row = row0 + ty * 4 + i;
    if (row < M) {
      float4 o = {acc[i][0] + b4.x, acc[i][1] + b4.y, acc[i][2] + b4.z, acc[i][3] + b4.w};
      *(float4*)(C + (long)row * NC + col0 + tx * 4) = o;
    }
  }
}

// ---------------- BatchNorm (train-mode, biased var) + ReLU ------------------
__global__ void bn_stats(const float* __restrict__ x, float* __restrict__ gsum,
                         float* __restrict__ gsq, int N) {
  int c = threadIdx.x;
  int r0 = blockIdx.x * 128;
  int r1 = min(r0 + 128, N);
  float s = 0.f, q = 0.f;
  for (int r = r0; r < r1; ++r) {
    float v = x[(long)r * 256 + c];
    s += v;
    q += v * v;
  }
  atomicAdd(&gsum[c], s);
  atomicAdd(&gsq[c], q);
}

__global__ void bn_finalize(const float* __restrict__ gsum, const float* __restrict__ gsq,
                            const float* __restrict__ gamma, const float* __restrict__ beta,
                            float* __restrict__ scale, float* __restrict__ shift, float invN) {
  int c = threadIdx.x;
  float mean = gsum[c] * invN;
  float var = fmaxf(gsq[c] * invN - mean * mean, 0.f);
  float sc = rsqrtf(var + BN_EPS) * gamma[c];
  scale[c] = sc;
  shift[c] = beta[c] - mean * sc;
}

// BN apply + ReLU, fp32 in -> fp16 out. 8 channels per thread; 256 channels.
__global__ void bn_apply_h(const float4* __restrict__ x, float4* __restrict__ h,
                           const float4* __restrict__ scale4, const float4* __restrict__ shift4,
                           long total8) {
  long t = (long)blockIdx.x * blockDim.x + threadIdx.x;
  if (t >= total8) return;
  float4 a = x[2 * t], b = x[2 * t + 1];
  int c8 = (int)(t & 31);  // which 8-channel chunk of 256
  float4 sc0 = scale4[2 * c8], sh0 = shift4[2 * c8];
  float4 sc1 = scale4[2 * c8 + 1], sh1 = shift4[2 * c8 + 1];
  HF4 o;
  o.h[0] = __floats2half2_rn(fmaxf(a.x * sc0.x + sh0.x, 0.f), fmaxf(a.y * sc0.y + sh0.y, 0.f));
  o.h[1] = __floats2half2_rn(fmaxf(a.z * sc0.z + sh0.z, 0.f), fmaxf(a.w * sc0.w + sh0.w, 0.f));
  o.h[2] = __floats2half2_rn(fmaxf(b.x * sc1.x + sh1.x, 0.f), fmaxf(b.y * sc1.y + sh1.y, 0.f));
  o.h[3] = __floats2half2_rn(fmaxf(b.z * sc1.z + sh1.z, 0.f), fmaxf(b.w * sc1.w + sh1.w, 0.f));
  h[t] = o.f;
}

// ---------------- layer 2: P = H1 @ W2 (256 -> 2), fp16 H, wave per row ------
__global__ void gemm_small_h(const __half2* __restrict__ H, const float* __restrict__ W2,
                             float* __restrict__ P, int N) {
  int g = blockIdx.x * blockDim.x + threadIdx.x;
  int row = g >> 6;
  int lane = threadIdx.x & 63;
  if (row >= N) return;
  const __half2* h = H + (long)row * 128;  // 128 half2 = 256 dims
  float s0 = 0.f, s1 = 0.f;
#pragma unroll
  for (int kk = 0; kk < 2; ++kk) {
    int k2 = lane + kk * 64;
    float2 f = __half22float2(h[k2]);
    s0 += f.x * W2[4 * k2 + 0] + f.y * W2[4 * k2 + 2];
    s1 += f.x * W2[4 * k2 + 1] + f.y * W2[4 * k2 + 3];
  }
  for (int off = 32; off > 0; off >>= 1) {
    s0 += __shfl_down(s0, off, 64);
    s1 += __shfl_down(s1, off, 64);
  }
  if (lane == 0) {
    P[2 * row] = s0;
    P[2 * row + 1] = s1;
  }
}

__global__ void final_gather(const float* __restrict__ P, float* __restrict__ out,
                             const int* __restrict__ rowptr, const int* __restrict__ col,
                             const float* __restrict__ wgt, const float* __restrict__ dinv,
                             const float* __restrict__ b2, int N) {
  int n = blockIdx.x * blockDim.x + threadIdx.x;
  if (n >= N) return;
  float w = dinv[n] * dinv[n];
  float a0 = w * P[2 * n + 0];
  float a1 = w * P[2 * n + 1];
  int end = rowptr[n + 1];
  for (int j = rowptr[n]; j < end; ++j) {
    int s = col[j];
    float ww = wgt[j];
    a0 += ww * P[2 * s + 0];
    a1 += ww * P[2 * s + 1];
  }
  out[2 * n + 0] = a0 + b2[0];
  out[2 * n + 1] = a1 + b2[1];
}

// -----------------------------------------------------------------------------
extern "C" void kernel_launch(void* const* d_in, const int* in_sizes, int n_in,
                              void* d_out, int out_size, void* d_ws, size_t ws_size,
                              hipStream_t stream) {
  const float* x = (const float*)d_in[0];
  const void* eidx = d_in[1];
  const float* W0 = (const float*)d_in[2];
  const float* b0 = (const float*)d_in[3];
  const float* W1 = (const float*)d_in[4];
  const float* b1 = (const float*)d_in[5];
  const float* W2 = (const float*)d_in[6];
  const float* b2 = (const float*)d_in[7];
  const float* gamma0 = (const float*)d_in[8];
  const float* beta0 = (const float*)d_in[9];
  const float* gamma1 = (const float*)d_in[10];
  const float* beta1 = (const float*)d_in[11];

  const int N = in_sizes[0] / 128;  // 100000
  const int E = in_sizes[1] / 2;    // 1600000
  float* out = (float*)d_out;

  char* base = (char*)d_ws;
  size_t off = 0;
  auto alloc = [&](size_t bytes) {
    size_t o = off;
    off = (off + bytes + 255) & ~(size_t)255;
    return o;
  };
  const size_t o_col = alloc((size_t)E * 4);
  const size_t o_wgt = alloc((size_t)E * 4);
  const size_t o_rowptr = alloc((size_t)(N + 1) * 4);
  const size_t o_deg = alloc((size_t)N * 4);
  const size_t o_fill = alloc((size_t)N * 4);
  const size_t o_dinv = alloc((size_t)N * 4);
  const size_t o_blk = alloc(1024 * 4);
  const size_t o_flag = alloc(256);
  const size_t o_stats = alloc(4096);
  const size_t o_P = alloc((size_t)N * 2 * 4);
  const size_t o_A = alloc((size_t)N * 256 * 4);
  const size_t o_B = alloc((size_t)N * 256 * 4);

  int* col = (int*)(base + o_col);
  float* wgt = (float*)(base + o_wgt);
  int* rowptr = (int*)(base + o_rowptr);
  int* deg = (int*)(base + o_deg);
  int* fill = (int*)(base + o_fill);
  float* dinv = (float*)(base + o_dinv);
  int* blk = (int*)(base + o_blk);
  int* flag = (int*)(base + o_flag);
  float* gsum = (float*)(base + o_stats);
  float* gsq = gsum + 256;
  float* scale = gsum + 512;
  float* shift = gsum + 768;
  float* P = (float*)(base + o_P);
  float* bufA = (float*)(base + o_A);
  float* bufB = (float*)(base + o_B);
  // fp16 buffers, live-range overlapped with fp32 buffers:
  float4* xh = (float4*)(base + o_B);   // x fp16 (25.6MB); dead before gemm0 writes bufB
  float4* h0h = (float4*)(base + o_A);  // H0 fp16 (51.2MB); dead before gemm1 writes bufA
  float4* h1h = (float4*)(base + o_B);  // H1 fp16 (51.2MB); dead buffers after gemm1
  // edge index staging also overlaps bufB (dead before any fp16 use of that区):
  int* idx32 = (int*)(base + o_A);  // use bufA region: dead before agg0 writes bufA
  int* srcI = idx32;
  int* dstI = idx32 + E;

  auto cdiv = [](long a, long b) { return (int)((a + b - 1) / b); };
  const float invN = 1.0f / (float)N;
  const int B1 = cdiv(N, 1024);

  // 1. edge index -> int32 src/dst (staged in bufA region)
  hipLaunchKernelGGL(detect_i64, dim3(1), dim3(256), 0, stream, (const unsigned int*)eidx, flag);
  hipLaunchKernelGGL(convert_idx, dim3(cdiv(2L * E, 256)), dim3(256), 0, stream,
                     (const unsigned int*)eidx, flag, idx32, 2 * E);

  // 2. degrees -> dinv; CSR build. Also convert x -> fp16 (xh in bufB region).
  hipMemsetAsync(deg, 0, (size_t)N * 4, stream);
  hipMemsetAsync(fill, 0, (size_t)N * 4, stream);
  hipLaunchKernelGGL(deg_count, dim3(cdiv(E, 256)), dim3(256), 0, stream, dstI, deg, E);
  hipLaunchKernelGGL(make_dinv, dim3(cdiv(N, 256)), dim3(256), 0, stream, deg, dinv, N);
  hipLaunchKernelGGL(scan_partial, dim3(B1), dim3(256), 0, stream, deg, blk, N);
  hipLaunchKernelGGL(scan_blk, dim3(1), dim3(256), 0, stream, blk, B1);
  hipLaunchKernelGGL(scan_final, dim3(B1), dim3(256), 0, stream, deg, blk, rowptr, N, E);
  hipLaunchKernelGGL(csr_scatter, dim3(cdiv(E, 256)), dim3(256), 0, stream, srcI, dstI, dinv,
                     rowptr, fill, col, wgt, E);
  hipLaunchKernelGGL(f32_to_f16, dim3(cdiv((long)N * 16, 256)), dim3(256), 0, stream,
                     (const float4*)x, xh, (long)N * 16);

  // 3. layer 0: AX = A_hat @ x (128-dim fp16 gather, 16 lanes/node) -> bufA; GEMM -> bufB
  //    (idx32 in bufA region is dead now)
  hipLaunchKernelGGL((agg_gather_h<16>), dim3(cdiv((long)N * 16, 256)), dim3(256), 0, stream,
                     xh, (float4*)bufA, rowptr, col, wgt, dinv, N);
  hipLaunchKernelGGL(gemm_tile, dim3(cdiv(N, 64), 4), dim3(256), 0, stream, bufA, W0, b0, bufB,
                     N, 128, 256);

  // 4. BN0 + ReLU: stats on bufB, apply -> fp16 H0 (h0h, in bufA region)
  hipMemsetAsync(gsum, 0, 2048, stream);
  hipLaunchKernelGGL(bn_stats, dim3(cdiv(N, 128)), dim3(256), 0, stream, bufB, gsum, gsq, N);
  hipLaunchKernelGGL(bn_finalize, dim3(1), dim3(256), 0, stream, gsum, gsq, gamma0, beta0, scale,
                     shift, invN);
  hipLaunchKernelGGL(bn_apply_h, dim3(cdiv((long)N * 32, 256)), dim3(256), 0, stream,
                     (const float4*)bufB, h0h, (const float4*)scale, (const float4*)shift,
                     (long)N * 32);

  // 5. layer 1: AH0 (256-dim fp16 gather, 32 lanes/node) -> bufB; GEMM -> bufA
  hipLaunchKernelGGL((agg_gather_h<32>), dim3(cdiv((long)N * 32, 256)), dim3(256), 0, stream,
                     h0h, (float4*)bufB, rowptr, col, wgt, dinv, N);
  hipLaunchKernelGGL(gemm_tile, dim3(cdiv(N, 64), 4), dim3(256), 0, stream, bufB, W1, b1, bufA,
                     N, 256, 256);

  // 6. BN1 + ReLU: stats on bufA, apply -> fp16 H1 (h1h, in bufB region)
  hipMemsetAsync(gsum, 0, 2048, stream);
  hipLaunchKernelGGL(bn_stats, dim3(cdiv(N, 128)), dim3(256), 0, stream, bufA, gsum, gsq, N);
  hipLaunchKernelGGL(bn_finalize, dim3(1), dim3(256), 0, stream, gsum, gsq, gamma1, beta1, scale,
                     shift, invN);
  hipLaunchKernelGGL(bn_apply_h, dim3(cdiv((long)N * 32, 256)), dim3(256), 0, stream,
                     (const float4*)bufA, h1h, (const float4*)scale, (const float4*)shift,
                     (long)N * 32);

  // 7. layer 2: P = H1 @ W2 (256->2, fp16 H), then 2-dim CSR gather into d_out
  hipLaunchKernelGGL(gemm_small_h, dim3(cdiv((long)N * 64, 256)), dim3(256), 0, stream,
                     (const __half2*)h1h, W2, P, N);
  hipLaunchKernelGGL(final_gather, dim3(cdiv(N, 256)), dim3(256), 0, stream, P, out, rowptr, col,
                     wgt, dinv, b2, N);
}

// Round 4
// 717.743 us; speedup vs baseline: 12.2190x; 1.2114x over previous
//
#include <hip/hip_runtime.h>
#include <hip/hip_fp16.h>

// GCN 3-layer forward, MI355X.
// R1: atomics 8.8ms -> R2: CSR gather 1063us -> R3: fp16 gathers 869us.
// R4: f16 MFMA GEMMs (fp32 gemm_tile was 317us at MfmaUtil=0), fp16 agg output.

#define BN_EPS 1e-5f

union HF4 { float4 f; __half2 h[4]; };  // 8 halves in 16B

typedef __attribute__((ext_vector_type(8))) _Float16 f16x8;
typedef __attribute__((ext_vector_type(4))) float f32x4;

// ---------------- edge-index format probe (int32 vs int64 on device) --------
__global__ void detect_i64(const unsigned int* __restrict__ w, int* flag) {
  __shared__ unsigned int red[256];
  unsigned int v = 0;
  int t = threadIdx.x;
  for (int i = t; i < 1024; i += 256) v |= w[2 * i + 1];
  red[t] = v;
  __syncthreads();
  for (int s = 128; s > 0; s >>= 1) {
    if (t < s) red[t] |= red[t + s];
    __syncthreads();
  }
  if (t == 0) *flag = (red[0] == 0u) ? 1 : 0;
}

__global__ void convert_idx(const unsigned int* __restrict__ w, const int* __restrict__ flag,
                            int* __restrict__ out, int n) {
  int f = *flag;
  int i = blockIdx.x * blockDim.x + threadIdx.x;
  if (i < n) out[i] = (int)(f ? w[2 * (size_t)i] : w[i]);
}

// ---------------- degree / dinv ----------------------------------------------
__global__ void deg_count(const int* __restrict__ dst, int* __restrict__ deg, int E) {
  int i = blockIdx.x * blockDim.x + threadIdx.x;
  if (i < E) atomicAdd(&deg[dst[i]], 1);
}

__global__ void make_dinv(const int* __restrict__ deg, float* __restrict__ dinv, int N) {
  int i = blockIdx.x * blockDim.x + threadIdx.x;
  if (i < N) dinv[i] = rsqrtf((float)deg[i] + 1.0f);
}

// ---------------- prefix scan (tile = 1024) ----------------------------------
__global__ void scan_partial(const int* __restrict__ deg, int* __restrict__ blksum, int N) {
  __shared__ int s[256];
  int b = blockIdx.x, t = threadIdx.x;
  int base = b * 1024 + t * 4;
  int v = 0;
#pragma unroll
  for (int k = 0; k < 4; ++k) {
    int i = base + k;
    if (i < N) v += deg[i];
  }
  s[t] = v;
  __syncthreads();
  for (int st = 128; st > 0; st >>= 1) {
    if (t < st) s[t] += s[t + st];
    __syncthreads();
  }
  if (t == 0) blksum[b] = s[0];
}

__global__ void scan_blk(int* __restrict__ blksum, int B) {
  __shared__ int s[256];
  int t = threadIdx.x;
  int v = (t < B) ? blksum[t] : 0;
  s[t] = v;
  __syncthreads();
  for (int off = 1; off < 256; off <<= 1) {
    int u = (t >= off) ? s[t - off] : 0;
    __syncthreads();
    s[t] += u;
    __syncthreads();
  }
  if (t < B) blksum[t] = s[t] - v;
}

__global__ void scan_final(const int* __restrict__ deg, const int* __restrict__ blkoff,
                           int* __restrict__ rowptr, int N, int E) {
  __shared__ int s[256];
  int b = blockIdx.x, t = threadIdx.x;
  int base = b * 1024 + t * 4;
  int v[4];
  int sum = 0;
#pragma unroll
  for (int k = 0; k < 4; ++k) {
    int i = base + k;
    v[k] = (i < N) ? deg[i] : 0;
    sum += v[k];
  }
  s[t] = sum;
  __syncthreads();
  for (int off = 1; off < 256; off <<= 1) {
    int u = (t >= off) ? s[t - off] : 0;
    __syncthreads();
    s[t] += u;
    __syncthreads();
  }
  int ex = s[t] - sum + blkoff[b];
#pragma unroll
  for (int k = 0; k < 4; ++k) {
    int i = base + k;
    if (i < N) {
      rowptr[i] = ex;
      ex += v[k];
    }
  }
  if (b == 0 && t == 0) rowptr[N] = E;
}

// ---------------- CSR scatter -------------------------------------------------
__global__ void csr_scatter(const int* __restrict__ src, const int* __restrict__ dst,
                            const float* __restrict__ dinv, const int* __restrict__ rowptr,
                            int* __restrict__ fill, int* __restrict__ col,
                            float* __restrict__ wgt, int E) {
  int e = blockIdx.x * blockDim.x + threadIdx.x;
  if (e >= E) return;
  int s = src[e], d = dst[e];
  int pos = atomicAdd(&fill[d], 1);
  int slot = rowptr[d] + pos;
  col[slot] = s;
  wgt[slot] = dinv[s] * dinv[d];
}

// ---------------- fp32 -> fp16 convert (8 elems/thread) ----------------------
__global__ void f32_to_f16(const float4* __restrict__ in, float4* __restrict__ outh, long n8) {
  long t = (long)blockIdx.x * blockDim.x + threadIdx.x;
  if (t >= n8) return;
  float4 a = in[2 * t], b = in[2 * t + 1];
  HF4 o;
  o.h[0] = __floats2half2_rn(a.x, a.y);
  o.h[1] = __floats2half2_rn(a.z, a.w);
  o.h[2] = __floats2half2_rn(b.x, b.y);
  o.h[3] = __floats2half2_rn(b.z, b.w);
  outh[t] = o.f;
}

// ---------------- weight pre-pack into B-fragment order ----------------------
// Wpack flat idx: (((k>>5)*4 + (k&31)>>3)*NC + n)*8 + (k&7)
__global__ void pack_w(const float* __restrict__ W, _Float16* __restrict__ Wp, int K, int NC) {
  int idx = blockIdx.x * blockDim.x + threadIdx.x;
  if (idx >= K * NC) return;
  int k = idx / NC, n = idx - k * NC;
  int kb = k >> 5, kk = k & 31, seg = kk >> 3, j = kk & 7;
  Wp[(((kb * 4 + seg) * NC) + n) * 8 + j] = (_Float16)W[idx];
}

// ---------------- gather aggregation (fp16 in, fp16 out, fp32 accum) ---------
// LPN lanes per node, each lane owns 8 halves (16B). F = 8*LPN.
template <int LPN>
__global__ void agg_gather_h(const float4* __restrict__ inh, float4* __restrict__ outh,
                             const int* __restrict__ rowptr, const int* __restrict__ col,
                             const float* __restrict__ wgt, const float* __restrict__ dinv,
                             int N) {
  long g = (long)blockIdx.x * blockDim.x + threadIdx.x;
  int n = (int)(g / LPN);
  int lane = (int)(g & (LPN - 1));
  if (n >= N) return;
  float ws = dinv[n];
  ws *= ws;
  float acc[8];
  {
    HF4 u;
    u.f = inh[(long)n * LPN + lane];
#pragma unroll
    for (int i = 0; i < 4; ++i) {
      float2 f = __half22float2(u.h[i]);
      acc[2 * i] = ws * f.x;
      acc[2 * i + 1] = ws * f.y;
    }
  }
  int beg = rowptr[n], end = rowptr[n + 1];
  int j = beg;
  for (; j + 1 < end; j += 2) {
    int s0 = col[j], s1 = col[j + 1];
    float w0 = wgt[j], w1 = wgt[j + 1];
    HF4 a, b;
    a.f = inh[(long)s0 * LPN + lane];
    b.f = inh[(long)s1 * LPN + lane];
#pragma unroll
    for (int i = 0; i < 4; ++i) {
      float2 fa = __half22float2(a.h[i]);
      float2 fb = __half22float2(b.h[i]);
      acc[2 * i] += w0 * fa.x + w1 * fb.x;
      acc[2 * i + 1] += w0 * fa.y + w1 * fb.y;
    }
  }
  if (j < end) {
    int s0 = col[j];
    float w0 = wgt[j];
    HF4 a;
    a.f = inh[(long)s0 * LPN + lane];
#pragma unroll
    for (int i = 0; i < 4; ++i) {
      float2 fa = __half22float2(a.h[i]);
      acc[2 * i] += w0 * fa.x;
      acc[2 * i + 1] += w0 * fa.y;
    }
  }
  HF4 o;
  o.h[0] = __floats2half2_rn(acc[0], acc[1]);
  o.h[1] = __floats2half2_rn(acc[2], acc[3]);
  o.h[2] = __floats2half2_rn(acc[4], acc[5]);
  o.h[3] = __floats2half2_rn(acc[6], acc[7]);
  outh[(long)n * LPN + lane] = o.f;
}

// ---------------- f16 MFMA GEMM: C[M,NC] = A[M,K]@W[K,NC] + bias -------------
// A fp16 row-major; Wpack in B-frag order; C fp32. Wave = 16 rows x NC cols.
// Frag layouts (verified, learn_hip m89): A/B lane holds 8 contiguous k at
// seg=lane>>4; C/D: col=lane&15, row=seg*4+reg.
template <int K, int NC>
__global__ __launch_bounds__(256) void gemm_mfma(const _Float16* __restrict__ A,
                                                 const float4* __restrict__ Wpack,
                                                 const float* __restrict__ bias,
                                                 float* __restrict__ C, int M) {
  int wave = threadIdx.x >> 6;
  int lane = threadIdx.x & 63;
  int row0 = (blockIdx.x * 4 + wave) * 16;
  if (row0 >= M) return;
  int r = lane & 15;
  int seg = lane >> 4;
  f32x4 acc[NC / 16];
#pragma unroll
  for (int t = 0; t < NC / 16; ++t) acc[t] = (f32x4){0.f, 0.f, 0.f, 0.f};
  const _Float16* arow = A + (long)(row0 + r) * K;
#pragma unroll
  for (int k0 = 0; k0 < K; k0 += 32) {
    f16x8 af = *(const f16x8*)(arow + k0 + seg * 8);
    const float4* wp = Wpack + ((k0 >> 5) * 4 + seg) * NC;
#pragma unroll
    for (int t = 0; t < NC / 16; ++t) {
      f16x8 bf = *(const f16x8*)(wp + t * 16 + r);
      acc[t] = __builtin_amdgcn_mfma_f32_16x16x32_f16(af, bf, acc[t], 0, 0, 0);
    }
  }
  int crow = row0 + seg * 4;
#pragma unroll
  for (int t = 0; t < NC / 16; ++t) {
    float bv = bias[t * 16 + r];
#pragma unroll
    for (int q = 0; q < 4; ++q) {
      C[(long)(crow + q) * NC + t * 16 + r] = acc[t][q] + bv;
    }
  }
}

// ---------------- BatchNorm (train-mode, biased var) + ReLU ------------------
__global__ void bn_stats(const float* __restrict__ x, float* __restrict__ gsum,
                         float* __restrict__ gsq, int N) {
  int c = threadIdx.x;
  int r0 = blockIdx.x * 128;
  int r1 = min(r0 + 128, N);
  float s = 0.f, q = 0.f;
  for (int r = r0; r < r1; ++r) {
    float v = x[(long)r * 256 + c];
    s += v;
    q += v * v;
  }
  atomicAdd(&gsum[c], s);
  atomicAdd(&gsq[c], q);
}

__global__ void bn_finalize(const float* __restrict__ gsum, const float* __restrict__ gsq,
                            const float* __restrict__ gamma, const float* __restrict__ beta,
                            float* __restrict__ scale, float* __restrict__ shift, float invN) {
  int c = threadIdx.x;
  float mean = gsum[c] * invN;
  float var = fmaxf(gsq[c] * invN - mean * mean, 0.f);
  float sc = rsqrtf(var + BN_EPS) * gamma[c];
  scale[c] = sc;
  shift[c] = beta[c] - mean * sc;
}

// BN apply + ReLU, fp32 in -> fp16 out. 8 channels per thread; 256 channels.
__global__ void bn_apply_h(const float4* __restrict__ x, float4* __restrict__ h,
                           const float4* __restrict__ scale4, const float4* __restrict__ shift4,
                           long total8) {
  long t = (long)blockIdx.x * blockDim.x + threadIdx.x;
  if (t >= total8) return;
  float4 a = x[2 * t], b = x[2 * t + 1];
  int c8 = (int)(t & 31);
  float4 sc0 = scale4[2 * c8], sh0 = shift4[2 * c8];
  float4 sc1 = scale4[2 * c8 + 1], sh1 = shift4[2 * c8 + 1];
  HF4 o;
  o.h[0] = __floats2half2_rn(fmaxf(a.x * sc0.x + sh0.x, 0.f), fmaxf(a.y * sc0.y + sh0.y, 0.f));
  o.h[1] = __floats2half2_rn(fmaxf(a.z * sc0.z + sh0.z, 0.f), fmaxf(a.w * sc0.w + sh0.w, 0.f));
  o.h[2] = __floats2half2_rn(fmaxf(b.x * sc1.x + sh1.x, 0.f), fmaxf(b.y * sc1.y + sh1.y, 0.f));
  o.h[3] = __floats2half2_rn(fmaxf(b.z * sc1.z + sh1.z, 0.f), fmaxf(b.w * sc1.w + sh1.w, 0.f));
  h[t] = o.f;
}

// ---------------- layer 2: P = H1 @ W2 (256 -> 2), fp16 H, wave per row ------
__global__ void gemm_small_h(const __half2* __restrict__ H, const float* __restrict__ W2,
                             float* __restrict__ P, int N) {
  int g = blockIdx.x * blockDim.x + threadIdx.x;
  int row = g >> 6;
  int lane = threadIdx.x & 63;
  if (row >= N) return;
  const __half2* h = H + (long)row * 128;
  float s0 = 0.f, s1 = 0.f;
#pragma unroll
  for (int kk = 0; kk < 2; ++kk) {
    int k2 = lane + kk * 64;
    float2 f = __half22float2(h[k2]);
    s0 += f.x * W2[4 * k2 + 0] + f.y * W2[4 * k2 + 2];
    s1 += f.x * W2[4 * k2 + 1] + f.y * W2[4 * k2 + 3];
  }
  for (int off = 32; off > 0; off >>= 1) {
    s0 += __shfl_down(s0, off, 64);
    s1 += __shfl_down(s1, off, 64);
  }
  if (lane == 0) {
    P[2 * row] = s0;
    P[2 * row + 1] = s1;
  }
}

__global__ void final_gather(const float* __restrict__ P, float* __restrict__ out,
                             const int* __restrict__ rowptr, const int* __restrict__ col,
                             const float* __restrict__ wgt, const float* __restrict__ dinv,
                             const float* __restrict__ b2, int N) {
  int n = blockIdx.x * blockDim.x + threadIdx.x;
  if (n >= N) return;
  float w = dinv[n] * dinv[n];
  float a0 = w * P[2 * n + 0];
  float a1 = w * P[2 * n + 1];
  int end = rowptr[n + 1];
  for (int j = rowptr[n]; j < end; ++j) {
    int s = col[j];
    float ww = wgt[j];
    a0 += ww * P[2 * s + 0];
    a1 += ww * P[2 * s + 1];
  }
  out[2 * n + 0] = a0 + b2[0];
  out[2 * n + 1] = a1 + b2[1];
}

// -----------------------------------------------------------------------------
extern "C" void kernel_launch(void* const* d_in, const int* in_sizes, int n_in,
                              void* d_out, int out_size, void* d_ws, size_t ws_size,
                              hipStream_t stream) {
  const float* x = (const float*)d_in[0];
  const void* eidx = d_in[1];
  const float* W0 = (const float*)d_in[2];
  const float* b0 = (const float*)d_in[3];
  const float* W1 = (const float*)d_in[4];
  const float* b1 = (const float*)d_in[5];
  const float* W2 = (const float*)d_in[6];
  const float* b2 = (const float*)d_in[7];
  const float* gamma0 = (const float*)d_in[8];
  const float* beta0 = (const float*)d_in[9];
  const float* gamma1 = (const float*)d_in[10];
  const float* beta1 = (const float*)d_in[11];

  const int N = in_sizes[0] / 128;  // 100000
  const int E = in_sizes[1] / 2;    // 1600000
  float* out = (float*)d_out;

  char* base = (char*)d_ws;
  size_t off = 0;
  auto alloc = [&](size_t bytes) {
    size_t o = off;
    off = (off + bytes + 255) & ~(size_t)255;
    return o;
  };
  const size_t o_col = alloc((size_t)E * 4);
  const size_t o_wgt = alloc((size_t)E * 4);
  const size_t o_rowptr = alloc((size_t)(N + 1) * 4);
  const size_t o_deg = alloc((size_t)N * 4);
  const size_t o_fill = alloc((size_t)N * 4);
  const size_t o_dinv = alloc((size_t)N * 4);
  const size_t o_blk = alloc(1024 * 4);
  const size_t o_flag = alloc(256);
  const size_t o_stats = alloc(4096);
  const size_t o_P = alloc((size_t)N * 2 * 4);
  const size_t o_W0p = alloc(128 * 256 * 2);
  const size_t o_W1p = alloc(256 * 256 * 2);
  const size_t o_F32 = alloc((size_t)N * 256 * 4);  // fp32 GEMM outputs
  const size_t o_H1 = alloc((size_t)N * 256 * 2);   // fp16: xh -> h0h -> h1h
  const size_t o_H2 = alloc((size_t)N * 256 * 2);   // fp16: agg outputs (+idx staging)

  int* col = (int*)(base + o_col);
  float* wgt = (float*)(base + o_wgt);
  int* rowptr = (int*)(base + o_rowptr);
  int* deg = (int*)(base + o_deg);
  int* fill = (int*)(base + o_fill);
  float* dinv = (float*)(base + o_dinv);
  int* blk = (int*)(base + o_blk);
  int* flag = (int*)(base + o_flag);
  float* gsum = (float*)(base + o_stats);
  float* gsq = gsum + 256;
  float* scale = gsum + 512;
  float* shift = gsum + 768;
  float* P = (float*)(base + o_P);
  _Float16* W0p = (_Float16*)(base + o_W0p);
  _Float16* W1p = (_Float16*)(base + o_W1p);
  float* bufF = (float*)(base + o_F32);
  float4* H1 = (float4*)(base + o_H1);  // xh (N*128), later h0h/h1h (N*256)
  float4* H2 = (float4*)(base + o_H2);  // agg outputs
  int* idx32 = (int*)(base + o_H2);     // staging: dead before H2 first written
  int* srcI = idx32;
  int* dstI = idx32 + E;

  auto cdiv = [](long a, long b) { return (int)((a + b - 1) / b); };
  const float invN = 1.0f / (float)N;
  const int B1 = cdiv(N, 1024);

  // 1. edge index -> int32 src/dst (staged in H2 region)
  hipLaunchKernelGGL(detect_i64, dim3(1), dim3(256), 0, stream, (const unsigned int*)eidx, flag);
  hipLaunchKernelGGL(convert_idx, dim3(cdiv(2L * E, 256)), dim3(256), 0, stream,
                     (const unsigned int*)eidx, flag, idx32, 2 * E);

  // 2. degrees -> dinv; CSR build; weight packs; x -> fp16 (H1)
  hipMemsetAsync(deg, 0, (size_t)N * 4, stream);
  hipMemsetAsync(fill, 0, (size_t)N * 4, stream);
  hipLaunchKernelGGL(deg_count, dim3(cdiv(E, 256)), dim3(256), 0, stream, dstI, deg, E);
  hipLaunchKernelGGL(make_dinv, dim3(cdiv(N, 256)), dim3(256), 0, stream, deg, dinv, N);
  hipLaunchKernelGGL(scan_partial, dim3(B1), dim3(256), 0, stream, deg, blk, N);
  hipLaunchKernelGGL(scan_blk, dim3(1), dim3(256), 0, stream, blk, B1);
  hipLaunchKernelGGL(scan_final, dim3(B1), dim3(256), 0, stream, deg, blk, rowptr, N, E);
  hipLaunchKernelGGL(csr_scatter, dim3(cdiv(E, 256)), dim3(256), 0, stream, srcI, dstI, dinv,
                     rowptr, fill, col, wgt, E);
  hipLaunchKernelGGL(pack_w, dim3(cdiv(128 * 256, 256)), dim3(256), 0, stream, W0, W0p, 128, 256);
  hipLaunchKernelGGL(pack_w, dim3(cdiv(256 * 256, 256)), dim3(256), 0, stream, W1, W1p, 256, 256);
  hipLaunchKernelGGL(f32_to_f16, dim3(cdiv((long)N * 16, 256)), dim3(256), 0, stream,
                     (const float4*)x, H1, (long)N * 16);

  // 3. layer 0: agg (128-dim, fp16->fp16) H1 -> H2; MFMA GEMM -> bufF
  hipLaunchKernelGGL((agg_gather_h<16>), dim3(cdiv((long)N * 16, 256)), dim3(256), 0, stream,
                     H1, H2, rowptr, col, wgt, dinv, N);
  hipLaunchKernelGGL((gemm_mfma<128, 256>), dim3(cdiv(N, 64)), dim3(256), 0, stream,
                     (const _Float16*)H2, (const float4*)W0p, b0, bufF, N);

  // 4. BN0 + ReLU: stats on bufF, apply -> fp16 H0 (H1)
  hipMemsetAsync(gsum, 0, 2048, stream);
  hipLaunchKernelGGL(bn_stats, dim3(cdiv(N, 128)), dim3(256), 0, stream, bufF, gsum, gsq, N);
  hipLaunchKernelGGL(bn_finalize, dim3(1), dim3(256), 0, stream, gsum, gsq, gamma0, beta0, scale,
                     shift, invN);
  hipLaunchKernelGGL(bn_apply_h, dim3(cdiv((long)N * 32, 256)), dim3(256), 0, stream,
                     (const float4*)bufF, H1, (const float4*)scale, (const float4*)shift,
                     (long)N * 32);

  // 5. layer 1: agg (256-dim) H1 -> H2; MFMA GEMM -> bufF
  hipLaunchKernelGGL((agg_gather_h<32>), dim3(cdiv((long)N * 32, 256)), dim3(256), 0, stream,
                     H1, H2, rowptr, col, wgt, dinv, N);
  hipLaunchKernelGGL((gemm_mfma<256, 256>), dim3(cdiv(N, 64)), dim3(256), 0, stream,
                     (const _Float16*)H2, (const float4*)W1p, b1, bufF, N);

  // 6. BN1 + ReLU: stats on bufF, apply -> fp16 H1 (h1h)
  hipMemsetAsync(gsum, 0, 2048, stream);
  hipLaunchKernelGGL(bn_stats, dim3(cdiv(N, 128)), dim3(256), 0, stream, bufF, gsum, gsq, N);
  hipLaunchKernelGGL(bn_finalize, dim3(1), dim3(256), 0, stream, gsum, gsq, gamma1, beta1, scale,
                     shift, invN);
  hipLaunchKernelGGL(bn_apply_h, dim3(cdiv((long)N * 32, 256)), dim3(256), 0, stream,
                     (const float4*)bufF, H1, (const float4*)scale, (const float4*)shift,
                     (long)N * 32);

  // 7. layer 2: P = H1 @ W2 (256->2, fp16 H), then 2-dim CSR gather into d_out
  hipLaunchKernelGGL(gemm_small_h, dim3(cdiv((long)N * 64, 256)), dim3(256), 0, stream,
                     (const __half2*)H1, W2, P, N);
  hipLaunchKernelGGL(final_gather, dim3(cdiv(N, 256)), dim3(256), 0, stream, P, out, rowptr, col,
                     wgt, dinv, b2, N);
}

// Round 5
// 597.525 us; speedup vs baseline: 14.6774x; 1.2012x over previous
//
#include <hip/hip_runtime.h>
#include <hip/hip_fp16.h>

// GCN 3-layer forward, MI355X.
// R1 atomics 8.8ms -> R2 CSR gather 1063us -> R3 fp16 gathers 869us ->
// R4 f16 MFMA GEMMs 718us -> R5: fuse BN-stats into GEMM epilogue, fp16 GEMM
// out, fuse layer-2 projection into BN1-apply, 32 rows/wave GEMM, unroll agg.

#define BN_EPS 1e-5f

union HF4 { float4 f; __half2 h[4]; };  // 8 halves in 16B

typedef __attribute__((ext_vector_type(8))) _Float16 f16x8;
typedef __attribute__((ext_vector_type(4))) float f32x4;

// ---------------- edge-index format probe (int32 vs int64 on device) --------
__global__ void detect_i64(const unsigned int* __restrict__ w, int* flag) {
  __shared__ unsigned int red[256];
  unsigned int v = 0;
  int t = threadIdx.x;
  for (int i = t; i < 1024; i += 256) v |= w[2 * i + 1];
  red[t] = v;
  __syncthreads();
  for (int s = 128; s > 0; s >>= 1) {
    if (t < s) red[t] |= red[t + s];
    __syncthreads();
  }
  if (t == 0) *flag = (red[0] == 0u) ? 1 : 0;
}

// ---------------- edge convert + degree count (fused) ------------------------
__global__ void convert_deg(const unsigned int* __restrict__ w, const int* __restrict__ flag,
                            int* __restrict__ srcI, int* __restrict__ dstI,
                            int* __restrict__ deg, int E) {
  int i = blockIdx.x * blockDim.x + threadIdx.x;
  if (i >= E) return;
  int f = *flag;
  int s = (int)(f ? w[2 * (size_t)i] : w[i]);
  int d = (int)(f ? w[2 * ((size_t)E + i)] : w[(size_t)E + i]);
  srcI[i] = s;
  dstI[i] = d;
  atomicAdd(&deg[d], 1);
}

__global__ void make_dinv(const int* __restrict__ deg, float* __restrict__ dinv, int N) {
  int i = blockIdx.x * blockDim.x + threadIdx.x;
  if (i < N) dinv[i] = rsqrtf((float)deg[i] + 1.0f);
}

// ---------------- prefix scan (tile = 1024) ----------------------------------
__global__ void scan_partial(const int* __restrict__ deg, int* __restrict__ blksum, int N) {
  __shared__ int s[256];
  int b = blockIdx.x, t = threadIdx.x;
  int base = b * 1024 + t * 4;
  int v = 0;
#pragma unroll
  for (int k = 0; k < 4; ++k) {
    int i = base + k;
    if (i < N) v += deg[i];
  }
  s[t] = v;
  __syncthreads();
  for (int st = 128; st > 0; st >>= 1) {
    if (t < st) s[t] += s[t + st];
    __syncthreads();
  }
  if (t == 0) blksum[b] = s[0];
}

__global__ void scan_blk(int* __restrict__ blksum, int B) {
  __shared__ int s[256];
  int t = threadIdx.x;
  int v = (t < B) ? blksum[t] : 0;
  s[t] = v;
  __syncthreads();
  for (int off = 1; off < 256; off <<= 1) {
    int u = (t >= off) ? s[t - off] : 0;
    __syncthreads();
    s[t] += u;
    __syncthreads();
  }
  if (t < B) blksum[t] = s[t] - v;
}

__global__ void scan_final(const int* __restrict__ deg, const int* __restrict__ blkoff,
                           int* __restrict__ rowptr, int N, int E) {
  __shared__ int s[256];
  int b = blockIdx.x, t = threadIdx.x;
  int base = b * 1024 + t * 4;
  int v[4];
  int sum = 0;
#pragma unroll
  for (int k = 0; k < 4; ++k) {
    int i = base + k;
    v[k] = (i < N) ? deg[i] : 0;
    sum += v[k];
  }
  s[t] = sum;
  __syncthreads();
  for (int off = 1; off < 256; off <<= 1) {
    int u = (t >= off) ? s[t - off] : 0;
    __syncthreads();
    s[t] += u;
    __syncthreads();
  }
  int ex = s[t] - sum + blkoff[b];
#pragma unroll
  for (int k = 0; k < 4; ++k) {
    int i = base + k;
    if (i < N) {
      rowptr[i] = ex;
      ex += v[k];
    }
  }
  if (b == 0 && t == 0) rowptr[N] = E;
}

// ---------------- CSR scatter -------------------------------------------------
__global__ void csr_scatter(const int* __restrict__ src, const int* __restrict__ dst,
                            const float* __restrict__ dinv, const int* __restrict__ rowptr,
                            int* __restrict__ fill, int* __restrict__ col,
                            float* __restrict__ wgt, int E) {
  int e = blockIdx.x * blockDim.x + threadIdx.x;
  if (e >= E) return;
  int s = src[e], d = dst[e];
  int pos = atomicAdd(&fill[d], 1);
  int slot = rowptr[d] + pos;
  col[slot] = s;
  wgt[slot] = dinv[s] * dinv[d];
}

// ---------------- fp32 -> fp16 convert (8 elems/thread) ----------------------
__global__ void f32_to_f16(const float4* __restrict__ in, float4* __restrict__ outh, long n8) {
  long t = (long)blockIdx.x * blockDim.x + threadIdx.x;
  if (t >= n8) return;
  float4 a = in[2 * t], b = in[2 * t + 1];
  HF4 o;
  o.h[0] = __floats2half2_rn(a.x, a.y);
  o.h[1] = __floats2half2_rn(a.z, a.w);
  o.h[2] = __floats2half2_rn(b.x, b.y);
  o.h[3] = __floats2half2_rn(b.z, b.w);
  outh[t] = o.f;
}

// ---------------- weight pre-pack into B-fragment order ----------------------
// Wpack flat idx: (((k>>5)*4 + (k&31)>>3)*NC + n)*8 + (k&7)
__global__ void pack_w(const float* __restrict__ W, _Float16* __restrict__ Wp, int K, int NC) {
  int idx = blockIdx.x * blockDim.x + threadIdx.x;
  if (idx >= K * NC) return;
  int k = idx / NC, n = idx - k * NC;
  int kb = k >> 5, kk = k & 31, seg = kk >> 3, j = kk & 7;
  Wp[(((kb * 4 + seg) * NC) + n) * 8 + j] = (_Float16)W[idx];
}

// ---------------- gather aggregation (fp16 in, fp16 out, fp32 accum) ---------
// LPN lanes per node, each lane owns 8 halves (16B). F = 8*LPN.
template <int LPN>
__global__ void agg_gather_h(const float4* __restrict__ inh, float4* __restrict__ outh,
                             const int* __restrict__ rowptr, const int* __restrict__ col,
                             const float* __restrict__ wgt, const float* __restrict__ dinv,
                             int N) {
  long g = (long)blockIdx.x * blockDim.x + threadIdx.x;
  int n = (int)(g / LPN);
  int lane = (int)(g & (LPN - 1));
  if (n >= N) return;
  float ws = dinv[n];
  ws *= ws;
  float acc[8];
  {
    HF4 u;
    u.f = inh[(long)n * LPN + lane];
#pragma unroll
    for (int i = 0; i < 4; ++i) {
      float2 f = __half22float2(u.h[i]);
      acc[2 * i] = ws * f.x;
      acc[2 * i + 1] = ws * f.y;
    }
  }
  int beg = rowptr[n], end = rowptr[n + 1];
  int j = beg;
  for (; j + 3 < end; j += 4) {
    int s0 = col[j], s1 = col[j + 1], s2 = col[j + 2], s3 = col[j + 3];
    float w0 = wgt[j], w1 = wgt[j + 1], w2 = wgt[j + 2], w3 = wgt[j + 3];
    HF4 a, b, c, d;
    a.f = inh[(long)s0 * LPN + lane];
    b.f = inh[(long)s1 * LPN + lane];
    c.f = inh[(long)s2 * LPN + lane];
    d.f = inh[(long)s3 * LPN + lane];
#pragma unroll
    for (int i = 0; i < 4; ++i) {
      float2 fa = __half22float2(a.h[i]);
      float2 fb = __half22float2(b.h[i]);
      float2 fc = __half22float2(c.h[i]);
      float2 fd = __half22float2(d.h[i]);
      acc[2 * i] += w0 * fa.x + w1 * fb.x + w2 * fc.x + w3 * fd.x;
      acc[2 * i + 1] += w0 * fa.y + w1 * fb.y + w2 * fc.y + w3 * fd.y;
    }
  }
  for (; j < end; ++j) {
    int s0 = col[j];
    float w0 = wgt[j];
    HF4 a;
    a.f = inh[(long)s0 * LPN + lane];
#pragma unroll
    for (int i = 0; i < 4; ++i) {
      float2 fa = __half22float2(a.h[i]);
      acc[2 * i] += w0 * fa.x;
      acc[2 * i + 1] += w0 * fa.y;
    }
  }
  HF4 o;
  o.h[0] = __floats2half2_rn(acc[0], acc[1]);
  o.h[1] = __floats2half2_rn(acc[2], acc[3]);
  o.h[2] = __floats2half2_rn(acc[4], acc[5]);
  o.h[3] = __floats2half2_rn(acc[6], acc[7]);
  outh[(long)n * LPN + lane] = o.f;
}

// ---------------- f16 MFMA GEMM + fused BN stats -----------------------------
// H[M,NC](fp16) = A[M,K](fp16) @ Wpack; per-column sum/sumsq -> gsum/gsq.
// No bias: BN(h+b)==BN(h) exactly (per-channel shift cancels).
// Wave = 32 rows x NC cols. Frag layouts (verified m89): A/B lane holds 8
// contiguous k at seg=lane>>4; C/D: col=lane&15, row=seg*4+reg.
template <int K, int NC>
__global__ __launch_bounds__(256) void gemm_mfma(const _Float16* __restrict__ A,
                                                 const float4* __restrict__ Wpack,
                                                 _Float16* __restrict__ H,
                                                 float* __restrict__ gsum,
                                                 float* __restrict__ gsq, int M) {
  __shared__ float red0[NC];
  __shared__ float red1[NC];
  int tid = threadIdx.x;
  if (tid < NC) {
    red0[tid] = 0.f;
    red1[tid] = 0.f;
  }
  __syncthreads();
  int wave = tid >> 6;
  int lane = tid & 63;
  int row0 = (blockIdx.x * 4 + wave) * 32;
  bool active = row0 < M;
  int arow0 = active ? row0 : 0;
  int r = lane & 15;
  int seg = lane >> 4;
  f32x4 acc0[NC / 16], acc1[NC / 16];
#pragma unroll
  for (int t = 0; t < NC / 16; ++t) {
    acc0[t] = (f32x4){0.f, 0.f, 0.f, 0.f};
    acc1[t] = (f32x4){0.f, 0.f, 0.f, 0.f};
  }
  const _Float16* arowA = A + (long)(arow0 + r) * K;
  const _Float16* arowB = A + (long)(arow0 + 16 + r) * K;
#pragma unroll
  for (int k0 = 0; k0 < K; k0 += 32) {
    f16x8 af0 = *(const f16x8*)(arowA + k0 + seg * 8);
    f16x8 af1 = *(const f16x8*)(arowB + k0 + seg * 8);
    const float4* wp = Wpack + ((k0 >> 5) * 4 + seg) * NC;
#pragma unroll
    for (int t = 0; t < NC / 16; ++t) {
      f16x8 bf = *(const f16x8*)(wp + t * 16 + r);
      acc0[t] = __builtin_amdgcn_mfma_f32_16x16x32_f16(af0, bf, acc0[t], 0, 0, 0);
      acc1[t] = __builtin_amdgcn_mfma_f32_16x16x32_f16(af1, bf, acc1[t], 0, 0, 0);
    }
  }
#pragma unroll
  for (int t = 0; t < NC / 16; ++t) {
    int c = t * 16 + r;
    float s = 0.f, q = 0.f;
#pragma unroll
    for (int qq = 0; qq < 4; ++qq) {
      float v0 = acc0[t][qq], v1 = acc1[t][qq];
      s += v0 + v1;
      q += v0 * v0 + v1 * v1;
    }
    s += __shfl_xor(s, 16, 64);
    s += __shfl_xor(s, 32, 64);
    q += __shfl_xor(q, 16, 64);
    q += __shfl_xor(q, 32, 64);
    if (active) {
      if (seg == 0) {
        atomicAdd(&red0[c], s);
        atomicAdd(&red1[c], q);
      }
#pragma unroll
      for (int qq = 0; qq < 4; ++qq) {
        H[(long)(row0 + seg * 4 + qq) * NC + c] = (_Float16)acc0[t][qq];
        H[(long)(row0 + 16 + seg * 4 + qq) * NC + c] = (_Float16)acc1[t][qq];
      }
    }
  }
  __syncthreads();
  if (tid < NC) {
    atomicAdd(&gsum[tid], red0[tid]);
    atomicAdd(&gsq[tid], red1[tid]);
  }
}

// ---------------- BN finalize -------------------------------------------------
__global__ void bn_finalize(const float* __restrict__ gsum, const float* __restrict__ gsq,
                            const float* __restrict__ gamma, const float* __restrict__ beta,
                            float* __restrict__ scale, float* __restrict__ shift, float invN) {
  int c = threadIdx.x;
  float mean = gsum[c] * invN;
  float var = fmaxf(gsq[c] * invN - mean * mean, 0.f);
  float sc = rsqrtf(var + BN_EPS) * gamma[c];
  scale[c] = sc;
  shift[c] = beta[c] - mean * sc;
}

// ---------------- BN apply + ReLU, fp16 in -> fp16 out -----------------------
__global__ void bn_apply_h(const float4* __restrict__ h_in, float4* __restrict__ h_out,
                           const float4* __restrict__ scale4, const float4* __restrict__ shift4,
                           long total8) {
  long t = (long)blockIdx.x * blockDim.x + threadIdx.x;
  if (t >= total8) return;
  HF4 u;
  u.f = h_in[t];
  int c8 = (int)(t & 31);
  float4 sc0 = scale4[2 * c8], sh0 = shift4[2 * c8];
  float4 sc1 = scale4[2 * c8 + 1], sh1 = shift4[2 * c8 + 1];
  float2 f0 = __half22float2(u.h[0]);
  float2 f1 = __half22float2(u.h[1]);
  float2 f2 = __half22float2(u.h[2]);
  float2 f3 = __half22float2(u.h[3]);
  HF4 o;
  o.h[0] = __floats2half2_rn(fmaxf(f0.x * sc0.x + sh0.x, 0.f), fmaxf(f0.y * sc0.y + sh0.y, 0.f));
  o.h[1] = __floats2half2_rn(fmaxf(f1.x * sc0.z + sh0.z, 0.f), fmaxf(f1.y * sc0.w + sh0.w, 0.f));
  o.h[2] = __floats2half2_rn(fmaxf(f2.x * sc1.x + sh1.x, 0.f), fmaxf(f2.y * sc1.y + sh1.y, 0.f));
  o.h[3] = __floats2half2_rn(fmaxf(f3.x * sc1.z + sh1.z, 0.f), fmaxf(f3.y * sc1.w + sh1.w, 0.f));
  h_out[t] = o.f;
}

// ---------------- BN1 apply + ReLU + layer-2 projection (fused) --------------
// 8 rows/block, 32 lanes/row, 8 channels/lane. P[row] = relu(bn(h)) @ W2.
__global__ void bn_apply_proj(const float4* __restrict__ h_in, const float* __restrict__ scale,
                              const float* __restrict__ shift, const float* __restrict__ W2,
                              float* __restrict__ P, int N) {
  int tid = threadIdx.x;
  int row = blockIdx.x * 8 + (tid >> 5);
  int lr = tid & 31;
  if (row >= N) return;
  HF4 u;
  u.f = h_in[(long)row * 32 + lr];
  int c0 = lr * 8;
  float s0 = 0.f, s1 = 0.f;
#pragma unroll
  for (int i = 0; i < 4; ++i) {
    float2 f = __half22float2(u.h[i]);
    int ca = c0 + 2 * i, cb = c0 + 2 * i + 1;
    float va = fmaxf(f.x * scale[ca] + shift[ca], 0.f);
    float vb = fmaxf(f.y * scale[cb] + shift[cb], 0.f);
    s0 += va * W2[2 * ca] + vb * W2[2 * cb];
    s1 += va * W2[2 * ca + 1] + vb * W2[2 * cb + 1];
  }
#pragma unroll
  for (int off = 16; off > 0; off >>= 1) {
    s0 += __shfl_down(s0, off, 32);
    s1 += __shfl_down(s1, off, 32);
  }
  if (lr == 0) {
    P[2 * row] = s0;
    P[2 * row + 1] = s1;
  }
}

// ---------------- final 2-dim CSR gather -------------------------------------
__global__ void final_gather(const float* __restrict__ P, float* __restrict__ out,
                             const int* __restrict__ rowptr, const int* __restrict__ col,
                             const float* __restrict__ wgt, const float* __restrict__ dinv,
                             const float* __restrict__ b2, int N) {
  int n = blockIdx.x * blockDim.x + threadIdx.x;
  if (n >= N) return;
  float w = dinv[n] * dinv[n];
  float a0 = w * P[2 * n + 0];
  float a1 = w * P[2 * n + 1];
  int end = rowptr[n + 1];
  for (int j = rowptr[n]; j < end; ++j) {
    int s = col[j];
    float ww = wgt[j];
    a0 += ww * P[2 * s + 0];
    a1 += ww * P[2 * s + 1];
  }
  out[2 * n + 0] = a0 + b2[0];
  out[2 * n + 1] = a1 + b2[1];
}

// -----------------------------------------------------------------------------
extern "C" void kernel_launch(void* const* d_in, const int* in_sizes, int n_in,
                              void* d_out, int out_size, void* d_ws, size_t ws_size,
                              hipStream_t stream) {
  const float* x = (const float*)d_in[0];
  const void* eidx = d_in[1];
  const float* W0 = (const float*)d_in[2];
  const float* W1 = (const float*)d_in[4];
  const float* W2 = (const float*)d_in[6];
  const float* b2 = (const float*)d_in[7];
  const float* gamma0 = (const float*)d_in[8];
  const float* beta0 = (const float*)d_in[9];
  const float* gamma1 = (const float*)d_in[10];
  const float* beta1 = (const float*)d_in[11];

  const int N = in_sizes[0] / 128;  // 100000
  const int E = in_sizes[1] / 2;    // 1600000
  float* out = (float*)d_out;

  char* base = (char*)d_ws;
  size_t off = 0;
  auto alloc = [&](size_t bytes) {
    size_t o = off;
    off = (off + bytes + 255) & ~(size_t)255;
    return o;
  };
  const size_t o_col = alloc((size_t)E * 4);
  const size_t o_wgt = alloc((size_t)E * 4);
  const size_t o_rowptr = alloc((size_t)(N + 1) * 4);
  const size_t o_deg = alloc((size_t)N * 4);
  const size_t o_fill = alloc((size_t)N * 4);
  const size_t o_dinv = alloc((size_t)N * 4);
  const size_t o_blk = alloc(1024 * 4);
  const size_t o_flag = alloc(256);
  const size_t o_stats = alloc(4096);
  const size_t o_P = alloc((size_t)N * 2 * 4);
  const size_t o_W0p = alloc(128 * 256 * 2);
  const size_t o_W1p = alloc(256 * 256 * 2);
  const size_t o_H1 = alloc((size_t)N * 256 * 2);  // fp16 ping
  const size_t o_H2 = alloc((size_t)N * 256 * 2);  // fp16 pong (+idx staging)

  int* col = (int*)(base + o_col);
  float* wgt = (float*)(base + o_wgt);
  int* rowptr = (int*)(base + o_rowptr);
  int* deg = (int*)(base + o_deg);
  int* fill = (int*)(base + o_fill);
  float* dinv = (float*)(base + o_dinv);
  int* blk = (int*)(base + o_blk);
  int* flag = (int*)(base + o_flag);
  float* gsum = (float*)(base + o_stats);
  float* gsq = gsum + 256;
  float* scale = gsum + 512;
  float* shift = gsum + 768;
  float* P = (float*)(base + o_P);
  _Float16* W0p = (_Float16*)(base + o_W0p);
  _Float16* W1p = (_Float16*)(base + o_W1p);
  float4* H1 = (float4*)(base + o_H1);
  float4* H2 = (float4*)(base + o_H2);
  int* idx32 = (int*)(base + o_H2);  // staging: dead before H2 first written
  int* srcI = idx32;
  int* dstI = idx32 + E;

  auto cdiv = [](long a, long b) { return (int)((a + b - 1) / b); };
  const float invN = 1.0f / (float)N;
  const int B1 = cdiv(N, 1024);

  // 1. edge index -> int32 src/dst + degree count (fused)
  hipLaunchKernelGGL(detect_i64, dim3(1), dim3(256), 0, stream, (const unsigned int*)eidx, flag);
  hipMemsetAsync(deg, 0, (size_t)N * 4, stream);
  hipMemsetAsync(fill, 0, (size_t)N * 4, stream);
  hipLaunchKernelGGL(convert_deg, dim3(cdiv(E, 256)), dim3(256), 0, stream,
                     (const unsigned int*)eidx, flag, srcI, dstI, deg, E);

  // 2. dinv; CSR build; weight packs; x -> fp16 (H1)
  hipLaunchKernelGGL(make_dinv, dim3(cdiv(N, 256)), dim3(256), 0, stream, deg, dinv, N);
  hipLaunchKernelGGL(scan_partial, dim3(B1), dim3(256), 0, stream, deg, blk, N);
  hipLaunchKernelGGL(scan_blk, dim3(1), dim3(256), 0, stream, blk, B1);
  hipLaunchKernelGGL(scan_final, dim3(B1), dim3(256), 0, stream, deg, blk, rowptr, N, E);
  hipLaunchKernelGGL(csr_scatter, dim3(cdiv(E, 256)), dim3(256), 0, stream, srcI, dstI, dinv,
                     rowptr, fill, col, wgt, E);
  hipLaunchKernelGGL(pack_w, dim3(cdiv(128 * 256, 256)), dim3(256), 0, stream, W0, W0p, 128, 256);
  hipLaunchKernelGGL(pack_w, dim3(cdiv(256 * 256, 256)), dim3(256), 0, stream, W1, W1p, 256, 256);
  hipLaunchKernelGGL(f32_to_f16, dim3(cdiv((long)N * 16, 256)), dim3(256), 0, stream,
                     (const float4*)x, H1, (long)N * 16);

  // 3. layer 0: agg (128-dim) H1 -> H2; GEMM+stats -> H1 (fp16)
  hipLaunchKernelGGL((agg_gather_h<16>), dim3(cdiv((long)N * 16, 256)), dim3(256), 0, stream,
                     H1, H2, rowptr, col, wgt, dinv, N);
  hipMemsetAsync(gsum, 0, 2048, stream);
  hipLaunchKernelGGL((gemm_mfma<128, 256>), dim3(cdiv(N, 128)), dim3(256), 0, stream,
                     (const _Float16*)H2, (const float4*)W0p, (_Float16*)H1, gsum, gsq, N);

  // 4. BN0 + ReLU -> fp16 H0 (H2)
  hipLaunchKernelGGL(bn_finalize, dim3(1), dim3(256), 0, stream, gsum, gsq, gamma0, beta0, scale,
                     shift, invN);
  hipLaunchKernelGGL(bn_apply_h, dim3(cdiv((long)N * 32, 256)), dim3(256), 0, stream,
                     (const float4*)H1, H2, (const float4*)scale, (const float4*)shift,
                     (long)N * 32);

  // 5. layer 1: agg (256-dim) H2 -> H1; GEMM+stats -> H2 (fp16)
  hipLaunchKernelGGL((agg_gather_h<32>), dim3(cdiv((long)N * 32, 256)), dim3(256), 0, stream,
                     H2, H1, rowptr, col, wgt, dinv, N);
  hipMemsetAsync(gsum, 0, 2048, stream);
  hipLaunchKernelGGL((gemm_mfma<256, 256>), dim3(cdiv(N, 128)), dim3(256), 0, stream,
                     (const _Float16*)H1, (const float4*)W1p, (_Float16*)H2, gsum, gsq, N);

  // 6. BN1 + ReLU + layer-2 projection (fused) -> P
  hipLaunchKernelGGL(bn_finalize, dim3(1), dim3(256), 0, stream, gsum, gsq, gamma1, beta1, scale,
                     shift, invN);
  hipLaunchKernelGGL(bn_apply_proj, dim3(cdiv(N, 8)), dim3(256), 0, stream, (const float4*)H2,
                     scale, shift, W2, P, N);

  // 7. 2-dim CSR gather into d_out
  hipLaunchKernelGGL(final_gather, dim3(cdiv(N, 256)), dim3(256), 0, stream, P, out, rowptr, col,
                     wgt, dinv, b2, N);
}